// Round 3
// baseline (3124.126 us; speedup 1.0000x reference)
//
#include <hip/hip_runtime.h>
#include <hip/hip_cooperative_groups.h>

namespace cg = cooperative_groups;

#define N_NODES 20000
#define N_EDGES 320000
#define F_DIM   128
#define H_DIM   256
#define M_ROWS  4096
#define NQ      2048
#define NIT     32

// ---------------- helpers ----------------

__device__ __forceinline__ float wred(float v) {
#pragma unroll
  for (int m = 32; m > 0; m >>= 1) v += __shfl_xor(v, m, 64);
  return v;
}

__device__ __forceinline__ float bred256(float v, float* lds) {
  v = wred(v);
  int w = threadIdx.x >> 6;
  if ((threadIdx.x & 63) == 0) lds[w] = v;
  __syncthreads();
  float tot = lds[0] + lds[1] + lds[2] + lds[3];
  __syncthreads();
  return tot;
}

__device__ __forceinline__ unsigned short f2bf(float f) {
  unsigned u = __float_as_uint(f);
  unsigned r = u + 0x7fffu + ((u >> 16) & 1u);
  return (unsigned short)(r >> 16);
}
__device__ __forceinline__ float bflo(unsigned u) { return __uint_as_float(u << 16); }
__device__ __forceinline__ float bfhi(unsigned u) { return __uint_as_float(u & 0xffff0000u); }

// ---------------- CSR build ----------------

__global__ __launch_bounds__(256) void k_deg(const int* __restrict__ ei, int* __restrict__ deg) {
  int e = blockIdx.x * 256 + threadIdx.x;
  if (e < N_EDGES) atomicAdd(&deg[ei[e]], 1);
}

// scan + dinv fused
__global__ __launch_bounds__(1024) void k_scan(const int* __restrict__ deg,
    int* __restrict__ rowstart, float* __restrict__ dinv) {
  __shared__ int part[1024];
  int t = threadIdx.x;
  const int chunk = (N_NODES + 1023) / 1024;  // 20
  int lo = t * chunk;
  int hi = lo + chunk; if (hi > N_NODES) hi = N_NODES;
  int s = 0;
  for (int i = lo; i < hi; ++i) {
    int d = deg[i];
    dinv[i] = d > 0 ? rsqrtf((float)d) : 0.f;
    s += d;
  }
  part[t] = s;
  __syncthreads();
  for (int off = 1; off < 1024; off <<= 1) {
    int v = part[t];
    int add = (t >= off) ? part[t - off] : 0;
    __syncthreads();
    part[t] = v + add;
    __syncthreads();
  }
  int base = (t > 0) ? part[t - 1] : 0;
  for (int i = lo; i < hi; ++i) { rowstart[i] = base; base += deg[i]; }
  if (t == 0) rowstart[N_NODES] = part[1023];
}

__global__ __launch_bounds__(256) void k_scatter(const int* __restrict__ ei,
    const int* __restrict__ rowstart, int* __restrict__ cursor,
    const float* __restrict__ dinv, int* __restrict__ cols, float* __restrict__ wvals) {
  int e = blockIdx.x * 256 + threadIdx.x;
  if (e >= N_EDGES) return;
  int r = ei[e];
  int c = ei[N_EDGES + e];
  int pos = rowstart[r] + atomicAdd(&cursor[r], 1);
  cols[pos] = c;
  wvals[pos] = -dinv[r] * dinv[c];
}

// ---------------- GNN layer 1 ----------------

__global__ __launch_bounds__(256) void k_msg1(const float* __restrict__ x,
    const int* __restrict__ rowstart, const int* __restrict__ cols,
    const float* __restrict__ wvals, float* __restrict__ msg) {
  int wid = (blockIdx.x * 256 + threadIdx.x) >> 6;
  int lane = threadIdx.x & 63;
  if (wid >= N_NODES) return;
  int s0 = rowstart[wid], s1 = rowstart[wid + 1];
  const float2* x2 = (const float2*)x;
  float2 acc = make_float2(0.f, 0.f);
  for (int e = s0; e < s1; ++e) {
    int c = cols[e];
    float w = wvals[e];
    float2 xv = x2[(size_t)c * 64 + lane];
    acc.x += w * xv.x;
    acc.y += w * xv.y;
  }
  ((float2*)msg)[(size_t)wid * 64 + lane] = acc;
}

// h = relu(x@W10 + msg@W11 + b1); fused projection t += h.W20, s += h.W21
__global__ __launch_bounds__(256) void k_gemm1(const float* __restrict__ x,
    const float* __restrict__ msg, const float* __restrict__ W10,
    const float* __restrict__ W11, const float* __restrict__ b1,
    const float* __restrict__ W20, const float* __restrict__ W21,
    float* __restrict__ t, float* __restrict__ s) {
  __shared__ float As[32][68];
  __shared__ float Bs[32][68];
  const int row0 = blockIdx.x * 64;
  const int col0 = blockIdx.y * 64;
  const int tid = threadIdx.x;
  const int tx = tid & 15, ty = tid >> 4;
  float acc[4][4] = {};
  for (int pass = 0; pass < 2; ++pass) {
    const float* Am = pass ? msg : x;
    const float* Bm = pass ? W11 : W10;
    for (int k0 = 0; k0 < F_DIM; k0 += 32) {
#pragma unroll
      for (int e = 0; e < 8; ++e) {
        int idx = tid + e * 256;
        int i = idx >> 5, kk = idx & 31;
        int gr = row0 + i;
        As[kk][i] = (gr < N_NODES) ? Am[(size_t)gr * F_DIM + k0 + kk] : 0.f;
      }
#pragma unroll
      for (int e = 0; e < 8; ++e) {
        int idx = tid + e * 256;
        int kk = idx >> 6, j = idx & 63;
        Bs[kk][j] = Bm[(size_t)(k0 + kk) * H_DIM + col0 + j];
      }
      __syncthreads();
#pragma unroll
      for (int kk = 0; kk < 32; ++kk) {
        float4 a = *(const float4*)&As[kk][ty * 4];
        float4 b = *(const float4*)&Bs[kk][tx * 4];
        float av[4] = {a.x, a.y, a.z, a.w};
        float bv[4] = {b.x, b.y, b.z, b.w};
#pragma unroll
        for (int ii = 0; ii < 4; ++ii)
#pragma unroll
          for (int jj = 0; jj < 4; ++jj) acc[ii][jj] += av[ii] * bv[jj];
      }
      __syncthreads();
    }
  }
#pragma unroll
  for (int ii = 0; ii < 4; ++ii) {
    int gr = row0 + ty * 4 + ii;
    float tp = 0.f, sp = 0.f;
#pragma unroll
    for (int jj = 0; jj < 4; ++jj) {
      int c = col0 + tx * 4 + jj;
      float val = acc[ii][jj] + b1[c];
      val = val > 0.f ? val : 0.f;
      tp += val * W20[c];
      sp += val * W21[c];
    }
#pragma unroll
    for (int m = 1; m < 16; m <<= 1) {
      tp += __shfl_xor(tp, m, 64);
      sp += __shfl_xor(sp, m, 64);
    }
    if (tx == 0 && gr < N_NODES) {
      atomicAdd(&t[gr], tp);
      atomicAdd(&s[gr], sp);
    }
  }
}

// ---------------- GNN layer 2 scalar gather ----------------

__global__ __launch_bounds__(256) void k_h2(const float* __restrict__ t,
    const float* __restrict__ s, const int* __restrict__ rowstart,
    const int* __restrict__ cols, const float* __restrict__ wvals,
    const float* __restrict__ lamb, const float* __restrict__ b2, float* __restrict__ h2) {
  int i = blockIdx.x * 256 + threadIdx.x;
  if (i >= N_NODES) return;
  float m = 0.f;
  int s0 = rowstart[i], s1 = rowstart[i + 1];
  for (int e = s0; e < s1; ++e) m += wvals[e] * s[cols[e]];
  float val = t[i] + m + b2[0];
  val = val > 0.f ? val : 0.f;
  h2[i] = lamb[0] * val;
}

// ---------------- QP setup: bf16 convert A + b^T A partials ----------------

__global__ __launch_bounds__(256) void k_prep(const float* __restrict__ A,
    const float* __restrict__ b, unsigned* __restrict__ Au, float* __restrict__ btA_parts) {
  int jp = blockIdx.x * 256 + threadIdx.x;   // 0..1023 col pairs
  int k0 = blockIdx.y * 128;
  const float2* A2 = (const float2*)A;
  float acc0 = 0.f, acc1 = 0.f;
#pragma unroll 4
  for (int kk = 0; kk < 128; ++kk) {
    int k = k0 + kk;
    float2 a = A2[(size_t)k * 1024 + jp];
    float bk = b[k];
    acc0 += a.x * bk;
    acc1 += a.y * bk;
    unsigned lo = f2bf(a.x), hi = f2bf(a.y);
    Au[(size_t)k * 1024 + jp] = lo | (hi << 16);
  }
  ((float2*)(btA_parts + (size_t)blockIdx.y * NQ))[jp] = make_float2(acc0, acc1);
}

// rhs/q + CG-init (r, rr partials)
__global__ __launch_bounds__(256) void k_qrhs(const float* __restrict__ h2,
    const int* __restrict__ feat_ids, const float* __restrict__ x_prior,
    const float* __restrict__ btA_parts, float* __restrict__ q,
    float* __restrict__ r, float* __restrict__ rr_parts) {
  __shared__ float lds[4];
  int j = blockIdx.x * 256 + threadIdx.x;
  int f = feat_ids[j];
  float hf = h2[f] + 1e-5f;
  q[j] = hf;
  float bta = 0.f;
#pragma unroll
  for (int c = 0; c < 32; ++c) bta += btA_parts[(size_t)c * NQ + j];
  float rhsv = x_prior[j] * hf + bta;  // rhs = -p
  r[j] = rhsv;
  float tot = bred256(rhsv * rhsv, lds);
  if (threadIdx.x == 0) rr_parts[blockIdx.x] = tot;
}

// ---------------- fused CG: one cooperative kernel, 3 grid.syncs/iter ----
// grid = 256 blocks x 256 threads (1 block/CU). p lives in registers
// (each wave holds full p: pn[c][t] = p[c*512 + lane*8 + t]); x lives in
// owner-thread registers (thread gtid<2048 owns x[gtid]).
__global__ __launch_bounds__(256, 1) void k_cg(const unsigned* __restrict__ Au,
    const float* __restrict__ q, float* __restrict__ rvec, float* __restrict__ pg,
    float* __restrict__ v, float* __restrict__ Qp_parts, float* __restrict__ pAp_parts,
    float* __restrict__ rr_parts, float* __restrict__ out) {
  cg::grid_group grid = cg::this_grid();
  __shared__ float lds[4];
  const int tid = threadIdx.x;
  const int bid = blockIdx.x;
  const int gtid = bid * 256 + tid;
  const int wid = gtid >> 6;      // 0..1023
  const int lane = tid & 63;
  const int bx = bid & 3;         // phase-2 col group
  const int by = bid >> 2;        // phase-2 row chunk (64 rows)

  float pn[4][8];
  float xacc = 0.f;

  for (int k = 0; k < NIT; ++k) {
    // ---- phase 1: p update (registers) + v = A p ----
    const float4* r4 = (const float4*)rvec;
    if (k == 0) {
#pragma unroll
      for (int c = 0; c < 4; ++c) {
        int b4 = c * 128 + lane * 2;
#pragma unroll
        for (int hh = 0; hh < 2; ++hh) {
          float4 rv = r4[b4 + hh];
          pn[c][hh * 4 + 0] = rv.x; pn[c][hh * 4 + 1] = rv.y;
          pn[c][hh * 4 + 2] = rv.z; pn[c][hh * 4 + 3] = rv.w;
        }
      }
    } else {
      float rrn = 0.f, rro = 0.f;
#pragma unroll
      for (int i = 0; i < 8; ++i) {
        rrn += rr_parts[k * 8 + i];
        rro += rr_parts[(k - 1) * 8 + i];
      }
      float beta = rrn / rro;
#pragma unroll
      for (int c = 0; c < 4; ++c) {
        int b4 = c * 128 + lane * 2;
#pragma unroll
        for (int hh = 0; hh < 2; ++hh) {
          float4 rv = r4[b4 + hh];
          pn[c][hh * 4 + 0] = rv.x + beta * pn[c][hh * 4 + 0];
          pn[c][hh * 4 + 1] = rv.y + beta * pn[c][hh * 4 + 1];
          pn[c][hh * 4 + 2] = rv.z + beta * pn[c][hh * 4 + 2];
          pn[c][hh * 4 + 3] = rv.w + beta * pn[c][hh * 4 + 3];
        }
      }
    }
    // wave 0 persists p for column-indexed phases
    if (wid == 0) {
      float4* pg4 = (float4*)pg;
#pragma unroll
      for (int c = 0; c < 4; ++c) {
        pg4[c * 128 + lane * 2]     = make_float4(pn[c][0], pn[c][1], pn[c][2], pn[c][3]);
        pg4[c * 128 + lane * 2 + 1] = make_float4(pn[c][4], pn[c][5], pn[c][6], pn[c][7]);
      }
    }
    // matvec: 4 rows per wave
#pragma unroll
    for (int rr = 0; rr < 4; ++rr) {
      int row = wid * 4 + rr;
      const uint4* Ar = (const uint4*)(Au + (size_t)row * 1024);
      float acc = 0.f;
#pragma unroll
      for (int c = 0; c < 4; ++c) {
        uint4 av = Ar[c * 64 + lane];
        acc += bflo(av.x) * pn[c][0] + bfhi(av.x) * pn[c][1];
        acc += bflo(av.y) * pn[c][2] + bfhi(av.y) * pn[c][3];
        acc += bflo(av.z) * pn[c][4] + bfhi(av.z) * pn[c][5];
        acc += bflo(av.w) * pn[c][6] + bfhi(av.w) * pn[c][7];
      }
      acc = wred(acc);
      if (lane == 0) v[row] = acc;
    }
    grid.sync();

    // ---- phase 2: Qp partials (A^T v) + pAp partials ----
    {
      int jp = bx * 256 + tid;      // col pair
      int k0 = by * 64;
      float acc0 = 0.f, acc1 = 0.f;
#pragma unroll 8
      for (int kk = 0; kk < 64; ++kk) {
        unsigned a = Au[(size_t)(k0 + kk) * 1024 + jp];
        float vk = v[k0 + kk];
        acc0 += bflo(a) * vk;
        acc1 += bfhi(a) * vk;
      }
      ((float2*)Qp_parts)[(size_t)by * 1024 + jp] = make_float2(acc0, acc1);
      float2 p2 = ((const float2*)pg)[jp];
      float contrib = p2.x * acc0 + p2.y * acc1;
      if (by == 0) {
        float2 q2 = ((const float2*)q)[jp];
        contrib += q2.x * p2.x * p2.x + q2.y * p2.y * p2.y;
      }
      float tot = bred256(contrib, lds);
      if (tid == 0) pAp_parts[bid] = tot;
    }
    grid.sync();

    // ---- phase 3: alpha, x/r update, rr partials ----
    if (bid < 8) {
      int j = gtid;
      float pAp = bred256(pAp_parts[tid], lds);
      float rro = 0.f;
#pragma unroll
      for (int i = 0; i < 8; ++i) rro += rr_parts[k * 8 + i];
      float alpha = rro / pAp;
      float pj = pg[j];
      float Qpj = q[j] * pj;
#pragma unroll 8
      for (int c = 0; c < 64; ++c) Qpj += Qp_parts[(size_t)c * NQ + j];
      xacc += alpha * pj;
      float rj = rvec[j] - alpha * Qpj;
      rvec[j] = rj;
      if (k == NIT - 1) out[j] = xacc;
      float rrn = bred256(rj * rj, lds);
      if (tid == 0) rr_parts[(k + 1) * 8 + bid] = rrn;
    }
    grid.sync();
  }
}

// ---------------- launch ----------------

extern "C" void kernel_launch(void* const* d_in, const int* in_sizes, int n_in,
                              void* d_out, int out_size, void* d_ws, size_t ws_size,
                              hipStream_t stream) {
  const float* x      = (const float*)d_in[0];
  const int*   ei     = (const int*)d_in[1];
  const float* A      = (const float*)d_in[2];
  const float* b      = (const float*)d_in[3];
  const int*   fids   = (const int*)d_in[4];
  const float* xprior = (const float*)d_in[5];
  const float* lamb   = (const float*)d_in[6];
  const float* W10    = (const float*)d_in[7];
  const float* W11    = (const float*)d_in[8];
  const float* b1     = (const float*)d_in[9];
  const float* W20    = (const float*)d_in[10];
  const float* W21    = (const float*)d_in[11];
  const float* b2     = (const float*)d_in[12];
  float* out = (float*)d_out;

  char* base = (char*)d_ws;
  size_t o = 0;
  auto alloc = [&](size_t bytes) { size_t r = o; o = (o + bytes + 255) & ~size_t(255); return r; };

  // zero-init region first (deg, cursor, t, s)
  size_t off_deg    = alloc(N_NODES * 4);
  size_t off_cursor = alloc(N_NODES * 4);
  size_t off_t      = alloc(N_NODES * 4);
  size_t off_s      = alloc(N_NODES * 4);
  size_t zero_end   = o;
  size_t off_rowst  = alloc((N_NODES + 1) * 4);
  size_t off_dinv   = alloc(N_NODES * 4);
  size_t off_cols   = alloc(N_EDGES * 4);
  size_t off_wvals  = alloc(N_EDGES * 4);
  size_t off_msg1   = alloc((size_t)N_NODES * F_DIM * 4);
  size_t off_Abf    = alloc((size_t)M_ROWS * NQ * 2);
  size_t off_h2     = alloc(N_NODES * 4);
  size_t off_q      = alloc(NQ * 4);
  size_t off_r      = alloc(NQ * 4);
  size_t off_pg     = alloc(NQ * 4);
  size_t off_v      = alloc(M_ROWS * 4);
  size_t off_btAp   = alloc(32 * NQ * 4);
  size_t off_Qpp    = alloc(64 * NQ * 4);
  size_t off_pApp   = alloc(256 * 4);
  size_t off_rrp    = alloc((NIT + 1) * 8 * 4);
  if (o > ws_size) return;

  int*   deg      = (int*)(base + off_deg);
  int*   cursor   = (int*)(base + off_cursor);
  float* t        = (float*)(base + off_t);
  float* s        = (float*)(base + off_s);
  int*   rowstart = (int*)(base + off_rowst);
  float* dinv     = (float*)(base + off_dinv);
  int*   cols     = (int*)(base + off_cols);
  float* wvals    = (float*)(base + off_wvals);
  float* msg1     = (float*)(base + off_msg1);
  unsigned* Au    = (unsigned*)(base + off_Abf);
  float* h2       = (float*)(base + off_h2);
  float* q        = (float*)(base + off_q);
  float* rvec     = (float*)(base + off_r);
  float* pg       = (float*)(base + off_pg);
  float* v        = (float*)(base + off_v);
  float* btA_parts = (float*)(base + off_btAp);
  float* Qp_parts  = (float*)(base + off_Qpp);
  float* pAp_parts = (float*)(base + off_pApp);
  float* rr_parts  = (float*)(base + off_rrp);

  hipMemsetAsync(d_ws, 0, zero_end, stream);

  // CSR build
  k_deg<<<(N_EDGES + 255) / 256, 256, 0, stream>>>(ei, deg);
  k_scan<<<1, 1024, 0, stream>>>(deg, rowstart, dinv);
  k_scatter<<<(N_EDGES + 255) / 256, 256, 0, stream>>>(ei, rowstart, cursor, dinv, cols, wvals);

  // GNN
  k_msg1<<<N_NODES / 4, 256, 0, stream>>>(x, rowstart, cols, wvals, msg1);
  k_gemm1<<<dim3((N_NODES + 63) / 64, H_DIM / 64), 256, 0, stream>>>(
      x, msg1, W10, W11, b1, W20, W21, t, s);
  k_h2<<<(N_NODES + 255) / 256, 256, 0, stream>>>(t, s, rowstart, cols, wvals, lamb, b2, h2);

  // QP setup
  k_prep<<<dim3(4, 32), 256, 0, stream>>>(A, b, Au, btA_parts);
  k_qrhs<<<NQ / 256, 256, 0, stream>>>(h2, fids, xprior, btA_parts, q, rvec, rr_parts);

  // fused CG (cooperative)
  void* args[] = {(void*)&Au, (void*)&q, (void*)&rvec, (void*)&pg, (void*)&v,
                  (void*)&Qp_parts, (void*)&pAp_parts, (void*)&rr_parts, (void*)&out};
  hipLaunchCooperativeKernel((void*)k_cg, dim3(256), dim3(256), args, 0, stream);
}

// Round 4
// 628.241 us; speedup vs baseline: 4.9728x; 4.9728x over previous
//
#include <hip/hip_runtime.h>

#define N_NODES 20000
#define N_EDGES 320000
#define F_DIM   128
#define H_DIM   256
#define M_ROWS  4096
#define NQ      2048
#define NIT     28

// ---------------- helpers ----------------

__device__ __forceinline__ float wred(float v) {
#pragma unroll
  for (int m = 32; m > 0; m >>= 1) v += __shfl_xor(v, m, 64);
  return v;
}

__device__ __forceinline__ unsigned f2bf(float f) {
  unsigned u = __float_as_uint(f);
  unsigned r = u + 0x7fffu + ((u >> 16) & 1u);
  return r >> 16;
}
__device__ __forceinline__ float bflo(unsigned u) { return __uint_as_float(u << 16); }
__device__ __forceinline__ float bfhi(unsigned u) { return __uint_as_float(u & 0xffff0000u); }

// ---------------- CSR build ----------------

__global__ __launch_bounds__(256) void k_deg(const int* __restrict__ ei, int* __restrict__ deg) {
  int e = blockIdx.x * 256 + threadIdx.x;
  if (e < N_EDGES) atomicAdd(&deg[ei[e]], 1);
}

__global__ __launch_bounds__(1024) void k_scan(const int* __restrict__ deg,
    int* __restrict__ rowstart, float* __restrict__ dinv) {
  __shared__ int part[1024];
  int t = threadIdx.x;
  const int chunk = (N_NODES + 1023) / 1024;  // 20
  int lo = t * chunk;
  int hi = lo + chunk; if (hi > N_NODES) hi = N_NODES;
  int s = 0;
  for (int i = lo; i < hi; ++i) {
    int d = deg[i];
    dinv[i] = d > 0 ? rsqrtf((float)d) : 0.f;
    s += d;
  }
  part[t] = s;
  __syncthreads();
  for (int off = 1; off < 1024; off <<= 1) {
    int v = part[t];
    int add = (t >= off) ? part[t - off] : 0;
    __syncthreads();
    part[t] = v + add;
    __syncthreads();
  }
  int base = (t > 0) ? part[t - 1] : 0;
  for (int i = lo; i < hi; ++i) { rowstart[i] = base; base += deg[i]; }
  if (t == 0) rowstart[N_NODES] = part[1023];
}

__global__ __launch_bounds__(256) void k_scatter(const int* __restrict__ ei,
    const int* __restrict__ rowstart, int* __restrict__ cursor,
    const float* __restrict__ dinv, int* __restrict__ cols, float* __restrict__ wvals) {
  int e = blockIdx.x * 256 + threadIdx.x;
  if (e >= N_EDGES) return;
  int r = ei[e];
  int c = ei[N_EDGES + e];
  int pos = rowstart[r] + atomicAdd(&cursor[r], 1);
  cols[pos] = c;
  wvals[pos] = -dinv[r] * dinv[c];
}

// ---------------- GNN layer 1 ----------------

__global__ __launch_bounds__(256) void k_msg1(const float* __restrict__ x,
    const int* __restrict__ rowstart, const int* __restrict__ cols,
    const float* __restrict__ wvals, float* __restrict__ msg) {
  int wid = (blockIdx.x * 256 + threadIdx.x) >> 6;
  int lane = threadIdx.x & 63;
  if (wid >= N_NODES) return;
  int s0 = rowstart[wid], s1 = rowstart[wid + 1];
  const float2* x2 = (const float2*)x;
  float2 acc = make_float2(0.f, 0.f);
  for (int e = s0; e < s1; ++e) {
    int c = cols[e];
    float w = wvals[e];
    float2 xv = x2[(size_t)c * 64 + lane];
    acc.x += w * xv.x;
    acc.y += w * xv.y;
  }
  ((float2*)msg)[(size_t)wid * 64 + lane] = acc;
}

// h = relu(x@W10 + msg@W11 + b1); fused projection t += h.W20, s += h.W21
__global__ __launch_bounds__(256) void k_gemm1(const float* __restrict__ x,
    const float* __restrict__ msg, const float* __restrict__ W10,
    const float* __restrict__ W11, const float* __restrict__ b1,
    const float* __restrict__ W20, const float* __restrict__ W21,
    float* __restrict__ t, float* __restrict__ s) {
  __shared__ float As[32][68];
  __shared__ float Bs[32][68];
  const int row0 = blockIdx.x * 64;
  const int col0 = blockIdx.y * 64;
  const int tid = threadIdx.x;
  const int tx = tid & 15, ty = tid >> 4;
  float acc[4][4] = {};
  for (int pass = 0; pass < 2; ++pass) {
    const float* Am = pass ? msg : x;
    const float* Bm = pass ? W11 : W10;
    for (int k0 = 0; k0 < F_DIM; k0 += 32) {
#pragma unroll
      for (int e = 0; e < 8; ++e) {
        int idx = tid + e * 256;
        int i = idx >> 5, kk = idx & 31;
        int gr = row0 + i;
        As[kk][i] = (gr < N_NODES) ? Am[(size_t)gr * F_DIM + k0 + kk] : 0.f;
      }
#pragma unroll
      for (int e = 0; e < 8; ++e) {
        int idx = tid + e * 256;
        int kk = idx >> 6, j = idx & 63;
        Bs[kk][j] = Bm[(size_t)(k0 + kk) * H_DIM + col0 + j];
      }
      __syncthreads();
#pragma unroll
      for (int kk = 0; kk < 32; ++kk) {
        float4 a = *(const float4*)&As[kk][ty * 4];
        float4 b = *(const float4*)&Bs[kk][tx * 4];
        float av[4] = {a.x, a.y, a.z, a.w};
        float bv[4] = {b.x, b.y, b.z, b.w};
#pragma unroll
        for (int ii = 0; ii < 4; ++ii)
#pragma unroll
          for (int jj = 0; jj < 4; ++jj) acc[ii][jj] += av[ii] * bv[jj];
      }
      __syncthreads();
    }
  }
#pragma unroll
  for (int ii = 0; ii < 4; ++ii) {
    int gr = row0 + ty * 4 + ii;
    float tp = 0.f, sp = 0.f;
#pragma unroll
    for (int jj = 0; jj < 4; ++jj) {
      int c = col0 + tx * 4 + jj;
      float val = acc[ii][jj] + b1[c];
      val = val > 0.f ? val : 0.f;
      tp += val * W20[c];
      sp += val * W21[c];
    }
#pragma unroll
    for (int m = 1; m < 16; m <<= 1) {
      tp += __shfl_xor(tp, m, 64);
      sp += __shfl_xor(sp, m, 64);
    }
    if (tx == 0 && gr < N_NODES) {
      atomicAdd(&t[gr], tp);
      atomicAdd(&s[gr], sp);
    }
  }
}

// ---------------- GNN layer 2 scalar gather ----------------

__global__ __launch_bounds__(256) void k_h2(const float* __restrict__ t,
    const float* __restrict__ s, const int* __restrict__ rowstart,
    const int* __restrict__ cols, const float* __restrict__ wvals,
    const float* __restrict__ lamb, const float* __restrict__ b2, float* __restrict__ h2) {
  int i = blockIdx.x * 256 + threadIdx.x;
  if (i >= N_NODES) return;
  float m = 0.f;
  int s0 = rowstart[i], s1 = rowstart[i + 1];
  for (int e = s0; e < s1; ++e) m += wvals[e] * s[cols[e]];
  float val = t[i] + m + b2[0];
  val = val > 0.f ? val : 0.f;
  h2[i] = lamb[0] * val;
}

// ---------------- QP setup: bf16 A (row-major + transposed) + b^T A ------
// thread: col pair jp (0..1023), 128-row chunk by. Writes Au (row-major
// packed pairs of cols), Atu (col-major packed pairs of rows), btA partial.
__global__ __launch_bounds__(256) void k_prep(const float* __restrict__ A,
    const float* __restrict__ b, unsigned* __restrict__ Au,
    unsigned* __restrict__ Atu, float* __restrict__ btA_parts) {
  int jp = blockIdx.x * 256 + threadIdx.x;   // 0..1023
  int k0 = blockIdx.y * 128;
  const float2* A2 = (const float2*)A;
  float acc0 = 0.f, acc1 = 0.f;
  for (int kk = 0; kk < 128; kk += 8) {
    float ax[8], ay[8];
#pragma unroll
    for (int i = 0; i < 8; ++i) {
      int k = k0 + kk + i;
      float2 a = A2[(size_t)k * 1024 + jp];
      float bk = b[k];
      acc0 += a.x * bk;
      acc1 += a.y * bk;
      Au[(size_t)k * 1024 + jp] = f2bf(a.x) | (f2bf(a.y) << 16);
      ax[i] = a.x; ay[i] = a.y;
    }
    uint4 t0, t1;
    t0.x = f2bf(ax[0]) | (f2bf(ax[1]) << 16);
    t0.y = f2bf(ax[2]) | (f2bf(ax[3]) << 16);
    t0.z = f2bf(ax[4]) | (f2bf(ax[5]) << 16);
    t0.w = f2bf(ax[6]) | (f2bf(ax[7]) << 16);
    t1.x = f2bf(ay[0]) | (f2bf(ay[1]) << 16);
    t1.y = f2bf(ay[2]) | (f2bf(ay[3]) << 16);
    t1.z = f2bf(ay[4]) | (f2bf(ay[5]) << 16);
    t1.w = f2bf(ay[6]) | (f2bf(ay[7]) << 16);
    int uoff = (k0 + kk) >> 1;  // uint offset within At row, multiple of 4
    *(uint4*)(Atu + (size_t)(2 * jp) * 2048 + uoff) = t0;
    *(uint4*)(Atu + (size_t)(2 * jp + 1) * 2048 + uoff) = t1;
  }
  ((float2*)(btA_parts + (size_t)blockIdx.y * NQ))[jp] = make_float2(acc0, acc1);
}

// q, r0 = rhs
__global__ __launch_bounds__(256) void k_qrhs(const float* __restrict__ h2,
    const int* __restrict__ feat_ids, const float* __restrict__ x_prior,
    const float* __restrict__ btA_parts, float* __restrict__ q, float* __restrict__ r) {
  int j = blockIdx.x * 256 + threadIdx.x;
  int f = feat_ids[j];
  float hf = h2[f] + 1e-5f;
  q[j] = hf;
  float bta = 0.f;
#pragma unroll
  for (int c = 0; c < 32; ++c) bta += btA_parts[(size_t)c * NQ + j];
  r[j] = x_prior[j] * hf + bta;  // rhs = -p
}

// ---------------- CG kernel 1: scalars in-wave + p update + v = A p ------
// 1024 waves (256 blocks). Every wave holds full r/p/Qp in registers
// (j = c*512 + lane*8 + t) and redundantly computes alpha/beta/rr.
// Block 0 persists p_new (wave 0), r_new (wave 1), x update (wave 2).
__global__ __launch_bounds__(256) void k_cg1(int k, const unsigned* __restrict__ Au,
    const float* __restrict__ r_old, float* __restrict__ r_new,
    const float* __restrict__ p_old, float* __restrict__ p_new,
    const float* __restrict__ Qp, float* __restrict__ xcg,
    float* __restrict__ v) {
  const int tid = threadIdx.x, bid = blockIdx.x;
  const int gw = (bid * 256 + tid) >> 6;  // 0..1023
  const int lane = tid & 63;
  const int w = tid >> 6;

  float rn[4][8], pn[4][8];
  const float4* r4 = (const float4*)r_old;
#pragma unroll
  for (int c = 0; c < 4; ++c) {
#pragma unroll
    for (int hh = 0; hh < 2; ++hh) {
      float4 rv = r4[c * 128 + lane * 2 + hh];
      rn[c][hh * 4 + 0] = rv.x; rn[c][hh * 4 + 1] = rv.y;
      rn[c][hh * 4 + 2] = rv.z; rn[c][hh * 4 + 3] = rv.w;
    }
  }
  if (k == 0) {
#pragma unroll
    for (int c = 0; c < 4; ++c)
#pragma unroll
      for (int t = 0; t < 8; ++t) pn[c][t] = rn[c][t];
  } else {
    float qn[4][8];
    const float4* p4 = (const float4*)p_old;
    const float4* q4 = (const float4*)Qp;
#pragma unroll
    for (int c = 0; c < 4; ++c) {
#pragma unroll
      for (int hh = 0; hh < 2; ++hh) {
        float4 pv = p4[c * 128 + lane * 2 + hh];
        float4 qv = q4[c * 128 + lane * 2 + hh];
        pn[c][hh * 4 + 0] = pv.x; pn[c][hh * 4 + 1] = pv.y;
        pn[c][hh * 4 + 2] = pv.z; pn[c][hh * 4 + 3] = pv.w;
        qn[c][hh * 4 + 0] = qv.x; qn[c][hh * 4 + 1] = qv.y;
        qn[c][hh * 4 + 2] = qv.z; qn[c][hh * 4 + 3] = qv.w;
      }
    }
    float rr = 0.f, pap = 0.f;
#pragma unroll
    for (int c = 0; c < 4; ++c)
#pragma unroll
      for (int t = 0; t < 8; ++t) {
        rr += rn[c][t] * rn[c][t];
        pap += pn[c][t] * qn[c][t];
      }
    rr = wred(rr);
    pap = wred(pap);
    float alpha = rr / pap;
    // x += alpha * p_old (wave 2 of block 0, using pre-update register p)
    if (bid == 0 && w == 2) {
      float4* x4 = (float4*)xcg;
#pragma unroll
      for (int c = 0; c < 4; ++c) {
#pragma unroll
        for (int hh = 0; hh < 2; ++hh) {
          int i4 = c * 128 + lane * 2 + hh;
          float4 xv = x4[i4];
          xv.x += alpha * pn[c][hh * 4 + 0];
          xv.y += alpha * pn[c][hh * 4 + 1];
          xv.z += alpha * pn[c][hh * 4 + 2];
          xv.w += alpha * pn[c][hh * 4 + 3];
          x4[i4] = xv;
        }
      }
    }
    float rrn = 0.f;
#pragma unroll
    for (int c = 0; c < 4; ++c)
#pragma unroll
      for (int t = 0; t < 8; ++t) {
        rn[c][t] -= alpha * qn[c][t];
        rrn += rn[c][t] * rn[c][t];
      }
    rrn = wred(rrn);
    float beta = rrn / rr;
#pragma unroll
    for (int c = 0; c < 4; ++c)
#pragma unroll
      for (int t = 0; t < 8; ++t) pn[c][t] = rn[c][t] + beta * pn[c][t];
  }
  // persist p_new / r_new (block 0)
  if (bid == 0) {
    if (w == 0) {
      float4* d4 = (float4*)p_new;
#pragma unroll
      for (int c = 0; c < 4; ++c) {
        d4[c * 128 + lane * 2]     = make_float4(pn[c][0], pn[c][1], pn[c][2], pn[c][3]);
        d4[c * 128 + lane * 2 + 1] = make_float4(pn[c][4], pn[c][5], pn[c][6], pn[c][7]);
      }
    } else if (w == 1 && k > 0) {
      float4* d4 = (float4*)r_new;
#pragma unroll
      for (int c = 0; c < 4; ++c) {
        d4[c * 128 + lane * 2]     = make_float4(rn[c][0], rn[c][1], rn[c][2], rn[c][3]);
        d4[c * 128 + lane * 2 + 1] = make_float4(rn[c][4], rn[c][5], rn[c][6], rn[c][7]);
      }
    }
  }
  // v = A p_new : 4 rows per wave
  const uint4* Au4 = (const uint4*)Au;
#pragma unroll
  for (int rr2 = 0; rr2 < 4; ++rr2) {
    int row = gw * 4 + rr2;
    const uint4* Ar = Au4 + (size_t)row * 256;
    float acc = 0.f;
#pragma unroll
    for (int c = 0; c < 4; ++c) {
      uint4 av = Ar[c * 64 + lane];
      acc += bflo(av.x) * pn[c][0] + bfhi(av.x) * pn[c][1];
      acc += bflo(av.y) * pn[c][2] + bfhi(av.y) * pn[c][3];
      acc += bflo(av.z) * pn[c][4] + bfhi(av.z) * pn[c][5];
      acc += bflo(av.w) * pn[c][6] + bfhi(av.w) * pn[c][7];
    }
    acc = wred(acc);
    if (lane == 0) v[row] = acc;
  }
}

// ---------------- CG kernel 2: Qp = A^T v + q.p (full, via At) -----------
// 1024 waves, wave owns cols 2w, 2w+1. Full v in registers.
__global__ __launch_bounds__(256) void k_cg2(const unsigned* __restrict__ Atu,
    const float* __restrict__ v, const float* __restrict__ p_cur,
    const float* __restrict__ q, float* __restrict__ Qp) {
  const int gw = (blockIdx.x * 256 + threadIdx.x) >> 6;  // 0..1023
  const int lane = threadIdx.x & 63;
  float vn[8][8];
  const float4* v4 = (const float4*)v;
#pragma unroll
  for (int c = 0; c < 8; ++c) {
#pragma unroll
    for (int hh = 0; hh < 2; ++hh) {
      float4 vv = v4[c * 128 + lane * 2 + hh];
      vn[c][hh * 4 + 0] = vv.x; vn[c][hh * 4 + 1] = vv.y;
      vn[c][hh * 4 + 2] = vv.z; vn[c][hh * 4 + 3] = vv.w;
    }
  }
  const uint4* At4 = (const uint4*)Atu;
#pragma unroll
  for (int cc = 0; cc < 2; ++cc) {
    int j = gw * 2 + cc;
    const uint4* Ar = At4 + (size_t)j * 512;
    float acc = 0.f;
#pragma unroll
    for (int c = 0; c < 8; ++c) {
      uint4 av = Ar[c * 64 + lane];
      acc += bflo(av.x) * vn[c][0] + bfhi(av.x) * vn[c][1];
      acc += bflo(av.y) * vn[c][2] + bfhi(av.y) * vn[c][3];
      acc += bflo(av.z) * vn[c][4] + bfhi(av.z) * vn[c][5];
      acc += bflo(av.w) * vn[c][6] + bfhi(av.w) * vn[c][7];
    }
    acc = wred(acc);
    if (lane == 0) Qp[j] = acc + q[j] * p_cur[j];
  }
}

// ---------------- final: alpha + out = x + alpha p -----------------------
__global__ __launch_bounds__(256) void k_cgfin(const float* __restrict__ r_last,
    const float* __restrict__ p_last, const float* __restrict__ Qp,
    const float* __restrict__ xcg, float* __restrict__ out) {
  const int tid = threadIdx.x;
  const int lane = tid & 63;
  const float4* r4 = (const float4*)r_last;
  const float4* p4 = (const float4*)p_last;
  const float4* q4 = (const float4*)Qp;
  float rr = 0.f, pap = 0.f;
#pragma unroll
  for (int c = 0; c < 4; ++c) {
#pragma unroll
    for (int hh = 0; hh < 2; ++hh) {
      float4 rv = r4[c * 128 + lane * 2 + hh];
      float4 pv = p4[c * 128 + lane * 2 + hh];
      float4 qv = q4[c * 128 + lane * 2 + hh];
      rr += rv.x * rv.x + rv.y * rv.y + rv.z * rv.z + rv.w * rv.w;
      pap += pv.x * qv.x + pv.y * qv.y + pv.z * qv.z + pv.w * qv.w;
    }
  }
  rr = wred(rr);
  pap = wred(pap);
  float alpha = rr / pap;
  const float4* x4 = (const float4*)xcg;
  float4* o4 = (float4*)out;
#pragma unroll
  for (int hh = 0; hh < 2; ++hh) {
    int i4 = tid * 2 + hh;
    float4 xv = x4[i4];
    float4 pv = p4[i4];
    xv.x += alpha * pv.x; xv.y += alpha * pv.y;
    xv.z += alpha * pv.z; xv.w += alpha * pv.w;
    o4[i4] = xv;
  }
}

// ---------------- launch ----------------

extern "C" void kernel_launch(void* const* d_in, const int* in_sizes, int n_in,
                              void* d_out, int out_size, void* d_ws, size_t ws_size,
                              hipStream_t stream) {
  const float* x      = (const float*)d_in[0];
  const int*   ei     = (const int*)d_in[1];
  const float* A      = (const float*)d_in[2];
  const float* b      = (const float*)d_in[3];
  const int*   fids   = (const int*)d_in[4];
  const float* xprior = (const float*)d_in[5];
  const float* lamb   = (const float*)d_in[6];
  const float* W10    = (const float*)d_in[7];
  const float* W11    = (const float*)d_in[8];
  const float* b1     = (const float*)d_in[9];
  const float* W20    = (const float*)d_in[10];
  const float* W21    = (const float*)d_in[11];
  const float* b2     = (const float*)d_in[12];
  float* out = (float*)d_out;

  char* base = (char*)d_ws;
  size_t o = 0;
  auto alloc = [&](size_t bytes) { size_t r = o; o = (o + bytes + 255) & ~size_t(255); return r; };

  // zero-init region (deg, cursor, xcg, t, s)
  size_t off_deg    = alloc(N_NODES * 4);
  size_t off_cursor = alloc(N_NODES * 4);
  size_t off_xcg    = alloc(NQ * 4);
  size_t off_t      = alloc(N_NODES * 4);
  size_t off_s      = alloc(N_NODES * 4);
  size_t zero_end   = o;
  size_t off_rowst  = alloc((N_NODES + 1) * 4);
  size_t off_dinv   = alloc(N_NODES * 4);
  size_t off_h2     = alloc(N_NODES * 4);
  size_t off_q      = alloc(NQ * 4);
  size_t off_r0     = alloc(NQ * 4);
  size_t off_r1     = alloc(NQ * 4);
  size_t off_p0     = alloc(NQ * 4);
  size_t off_p1     = alloc(NQ * 4);
  size_t off_v      = alloc(M_ROWS * 4);
  size_t off_Qp     = alloc(NQ * 4);
  size_t off_btAp   = alloc(32 * NQ * 4);
  // union: {cols, wvals, msg1} (GNN phase)  vs  Atu (QP phase, written after k_h2)
  size_t union_sz_gnn = (size_t)N_EDGES * 4 + 256 + (size_t)N_EDGES * 4 + 256 +
                        (size_t)N_NODES * F_DIM * 4;
  size_t union_sz_at  = (size_t)M_ROWS * NQ * 2;
  size_t off_union  = alloc(union_sz_gnn > union_sz_at ? union_sz_gnn : union_sz_at);
  size_t off_Au     = alloc((size_t)M_ROWS * NQ * 2);
  if (o > ws_size) return;

  int*   deg      = (int*)(base + off_deg);
  int*   cursor   = (int*)(base + off_cursor);
  float* xcg      = (float*)(base + off_xcg);
  float* t        = (float*)(base + off_t);
  float* s        = (float*)(base + off_s);
  int*   rowstart = (int*)(base + off_rowst);
  float* dinv     = (float*)(base + off_dinv);
  float* h2       = (float*)(base + off_h2);
  float* q        = (float*)(base + off_q);
  float* rb[2]    = {(float*)(base + off_r0), (float*)(base + off_r1)};
  float* pg[2]    = {(float*)(base + off_p0), (float*)(base + off_p1)};
  float* v        = (float*)(base + off_v);
  float* Qp       = (float*)(base + off_Qp);
  float* btA_parts = (float*)(base + off_btAp);
  // union members
  int*   cols     = (int*)(base + off_union);
  float* wvals    = (float*)(base + off_union + (size_t)N_EDGES * 4 + 256);
  float* msg1     = (float*)(base + off_union + 2 * ((size_t)N_EDGES * 4 + 256));
  unsigned* Atu   = (unsigned*)(base + off_union);
  unsigned* Au    = (unsigned*)(base + off_Au);

  hipMemsetAsync(d_ws, 0, zero_end, stream);

  // CSR build
  k_deg<<<(N_EDGES + 255) / 256, 256, 0, stream>>>(ei, deg);
  k_scan<<<1, 1024, 0, stream>>>(deg, rowstart, dinv);
  k_scatter<<<(N_EDGES + 255) / 256, 256, 0, stream>>>(ei, rowstart, cursor, dinv, cols, wvals);

  // GNN
  k_msg1<<<N_NODES / 4, 256, 0, stream>>>(x, rowstart, cols, wvals, msg1);
  k_gemm1<<<dim3((N_NODES + 63) / 64, H_DIM / 64), 256, 0, stream>>>(
      x, msg1, W10, W11, b1, W20, W21, t, s);
  k_h2<<<(N_NODES + 255) / 256, 256, 0, stream>>>(t, s, rowstart, cols, wvals, lamb, b2, h2);

  // QP setup (after k_h2: Atu overwrites cols/wvals/msg1)
  k_prep<<<dim3(4, 32), 256, 0, stream>>>(A, b, Au, Atu, btA_parts);
  k_qrhs<<<NQ / 256, 256, 0, stream>>>(h2, fids, xprior, btA_parts, q, rb[0]);

  // CG: 2 kernels/iter
  k_cg1<<<256, 256, 0, stream>>>(0, Au, rb[0], rb[0], pg[0], pg[0], Qp, xcg, v);
  k_cg2<<<256, 256, 0, stream>>>(Atu, v, pg[0], q, Qp);
  for (int k = 1; k < NIT; ++k) {
    k_cg1<<<256, 256, 0, stream>>>(k, Au, rb[(k - 1) & 1], rb[k & 1],
                                   pg[(k - 1) & 1], pg[k & 1], Qp, xcg, v);
    k_cg2<<<256, 256, 0, stream>>>(Atu, v, pg[k & 1], q, Qp);
  }
  k_cgfin<<<1, 256, 0, stream>>>(rb[(NIT - 1) & 1], pg[(NIT - 1) & 1], Qp, xcg, out);
}

// Round 5
// 523.783 us; speedup vs baseline: 5.9645x; 1.1994x over previous
//
#include <hip/hip_runtime.h>

#define N_NODES 20000
#define N_EDGES 320000
#define F_DIM   128
#define H_DIM   256
#define M_ROWS  4096
#define NQ      2048
#define NIT     28

typedef __attribute__((ext_vector_type(8))) short short8;   // 8 bf16 (4 VGPRs)
typedef __attribute__((ext_vector_type(4))) float f32x4;    // MFMA C/D

// ---------------- helpers ----------------

__device__ __forceinline__ float wred(float v) {
#pragma unroll
  for (int m = 32; m > 0; m >>= 1) v += __shfl_xor(v, m, 64);
  return v;
}

__device__ __forceinline__ float bred256(float v, float* lds) {
  v = wred(v);
  int w = threadIdx.x >> 6;
  if ((threadIdx.x & 63) == 0) lds[w] = v;
  __syncthreads();
  float tot = lds[0] + lds[1] + lds[2] + lds[3];
  __syncthreads();
  return tot;
}

__device__ __forceinline__ unsigned f2bf(float f) {
  unsigned u = __float_as_uint(f);
  unsigned r = u + 0x7fffu + ((u >> 16) & 1u);
  return r >> 16;
}

// ---------------- CSR build ----------------

__global__ __launch_bounds__(256) void k_deg(const int* __restrict__ ei, int* __restrict__ deg) {
  int e = blockIdx.x * 256 + threadIdx.x;
  if (e < N_EDGES) atomicAdd(&deg[ei[e]], 1);
}

__global__ __launch_bounds__(1024) void k_scan(const int* __restrict__ deg,
    int* __restrict__ rowstart, float* __restrict__ dinv) {
  __shared__ int part[1024];
  int t = threadIdx.x;
  const int chunk = (N_NODES + 1023) / 1024;  // 20
  int lo = t * chunk;
  int hi = lo + chunk; if (hi > N_NODES) hi = N_NODES;
  int s = 0;
  for (int i = lo; i < hi; ++i) {
    int d = deg[i];
    dinv[i] = d > 0 ? rsqrtf((float)d) : 0.f;
    s += d;
  }
  part[t] = s;
  __syncthreads();
  for (int off = 1; off < 1024; off <<= 1) {
    int v = part[t];
    int add = (t >= off) ? part[t - off] : 0;
    __syncthreads();
    part[t] = v + add;
    __syncthreads();
  }
  int base = (t > 0) ? part[t - 1] : 0;
  for (int i = lo; i < hi; ++i) { rowstart[i] = base; base += deg[i]; }
  if (t == 0) rowstart[N_NODES] = part[1023];
}

__global__ __launch_bounds__(256) void k_scatter(const int* __restrict__ ei,
    const int* __restrict__ rowstart, int* __restrict__ cursor,
    const float* __restrict__ dinv, int* __restrict__ cols, float* __restrict__ wvals) {
  int e = blockIdx.x * 256 + threadIdx.x;
  if (e >= N_EDGES) return;
  int r = ei[e];
  int c = ei[N_EDGES + e];
  int pos = rowstart[r] + atomicAdd(&cursor[r], 1);
  cols[pos] = c;
  wvals[pos] = -dinv[r] * dinv[c];
}

// ---------------- GNN layer 1 ----------------

__global__ __launch_bounds__(256) void k_msg1(const float* __restrict__ x,
    const int* __restrict__ rowstart, const int* __restrict__ cols,
    const float* __restrict__ wvals, float* __restrict__ msg) {
  int wid = (blockIdx.x * 256 + threadIdx.x) >> 6;
  int lane = threadIdx.x & 63;
  if (wid >= N_NODES) return;
  int s0 = rowstart[wid], s1 = rowstart[wid + 1];
  const float2* x2 = (const float2*)x;
  float2 acc = make_float2(0.f, 0.f);
  for (int e = s0; e < s1; ++e) {
    int c = cols[e];
    float w = wvals[e];
    float2 xv = x2[(size_t)c * 64 + lane];
    acc.x += w * xv.x;
    acc.y += w * xv.y;
  }
  ((float2*)msg)[(size_t)wid * 64 + lane] = acc;
}

// h = relu(x@W10 + msg@W11 + b1); fused projection t += h.W20, s += h.W21
__global__ __launch_bounds__(256) void k_gemm1(const float* __restrict__ x,
    const float* __restrict__ msg, const float* __restrict__ W10,
    const float* __restrict__ W11, const float* __restrict__ b1,
    const float* __restrict__ W20, const float* __restrict__ W21,
    float* __restrict__ t, float* __restrict__ s) {
  __shared__ float As[32][68];
  __shared__ float Bs[32][68];
  const int row0 = blockIdx.x * 64;
  const int col0 = blockIdx.y * 64;
  const int tid = threadIdx.x;
  const int tx = tid & 15, ty = tid >> 4;
  float acc[4][4] = {};
  for (int pass = 0; pass < 2; ++pass) {
    const float* Am = pass ? msg : x;
    const float* Bm = pass ? W11 : W10;
    for (int k0 = 0; k0 < F_DIM; k0 += 32) {
#pragma unroll
      for (int e = 0; e < 8; ++e) {
        int idx = tid + e * 256;
        int i = idx >> 5, kk = idx & 31;
        int gr = row0 + i;
        As[kk][i] = (gr < N_NODES) ? Am[(size_t)gr * F_DIM + k0 + kk] : 0.f;
      }
#pragma unroll
      for (int e = 0; e < 8; ++e) {
        int idx = tid + e * 256;
        int kk = idx >> 6, j = idx & 63;
        Bs[kk][j] = Bm[(size_t)(k0 + kk) * H_DIM + col0 + j];
      }
      __syncthreads();
#pragma unroll
      for (int kk = 0; kk < 32; ++kk) {
        float4 a = *(const float4*)&As[kk][ty * 4];
        float4 b = *(const float4*)&Bs[kk][tx * 4];
        float av[4] = {a.x, a.y, a.z, a.w};
        float bv[4] = {b.x, b.y, b.z, b.w};
#pragma unroll
        for (int ii = 0; ii < 4; ++ii)
#pragma unroll
          for (int jj = 0; jj < 4; ++jj) acc[ii][jj] += av[ii] * bv[jj];
      }
      __syncthreads();
    }
  }
#pragma unroll
  for (int ii = 0; ii < 4; ++ii) {
    int gr = row0 + ty * 4 + ii;
    float tp = 0.f, sp = 0.f;
#pragma unroll
    for (int jj = 0; jj < 4; ++jj) {
      int c = col0 + tx * 4 + jj;
      float val = acc[ii][jj] + b1[c];
      val = val > 0.f ? val : 0.f;
      tp += val * W20[c];
      sp += val * W21[c];
    }
#pragma unroll
    for (int m = 1; m < 16; m <<= 1) {
      tp += __shfl_xor(tp, m, 64);
      sp += __shfl_xor(sp, m, 64);
    }
    if (tx == 0 && gr < N_NODES) {
      atomicAdd(&t[gr], tp);
      atomicAdd(&s[gr], sp);
    }
  }
}

// ---------------- GNN layer 2 scalar gather ----------------

__global__ __launch_bounds__(256) void k_h2(const float* __restrict__ t,
    const float* __restrict__ s, const int* __restrict__ rowstart,
    const int* __restrict__ cols, const float* __restrict__ wvals,
    const float* __restrict__ lamb, const float* __restrict__ b2, float* __restrict__ h2) {
  int i = blockIdx.x * 256 + threadIdx.x;
  if (i >= N_NODES) return;
  float m = 0.f;
  int s0 = rowstart[i], s1 = rowstart[i + 1];
  for (int e = s0; e < s1; ++e) m += wvals[e] * s[cols[e]];
  float val = t[i] + m + b2[0];
  val = val > 0.f ? val : 0.f;
  h2[i] = lamb[0] * val;
}

// ---------------- QP setup: bf16 A^T + b^T A partials ----------------
// Atu: row j (0..2047) = column j of A, 4096 bf16 packed in 2048 uints.
__global__ __launch_bounds__(256) void k_prep(const float* __restrict__ A,
    const float* __restrict__ b, unsigned* __restrict__ Atu, float* __restrict__ btA_parts) {
  int jp = blockIdx.x * 256 + threadIdx.x;   // 0..1023 col pairs
  int k0 = blockIdx.y * 128;
  const float2* A2 = (const float2*)A;
  float acc0 = 0.f, acc1 = 0.f;
  for (int kk = 0; kk < 128; kk += 8) {
    float ax[8], ay[8];
#pragma unroll
    for (int i = 0; i < 8; ++i) {
      int k = k0 + kk + i;
      float2 a = A2[(size_t)k * 1024 + jp];
      float bk = b[k];
      acc0 += a.x * bk;
      acc1 += a.y * bk;
      ax[i] = a.x; ay[i] = a.y;
    }
    uint4 t0, t1;
    t0.x = f2bf(ax[0]) | (f2bf(ax[1]) << 16);
    t0.y = f2bf(ax[2]) | (f2bf(ax[3]) << 16);
    t0.z = f2bf(ax[4]) | (f2bf(ax[5]) << 16);
    t0.w = f2bf(ax[6]) | (f2bf(ax[7]) << 16);
    t1.x = f2bf(ay[0]) | (f2bf(ay[1]) << 16);
    t1.y = f2bf(ay[2]) | (f2bf(ay[3]) << 16);
    t1.z = f2bf(ay[4]) | (f2bf(ay[5]) << 16);
    t1.w = f2bf(ay[6]) | (f2bf(ay[7]) << 16);
    int uoff = (k0 + kk) >> 1;
    *(uint4*)(Atu + (size_t)(2 * jp) * 2048 + uoff) = t0;
    *(uint4*)(Atu + (size_t)(2 * jp + 1) * 2048 + uoff) = t1;
  }
  ((float2*)(btA_parts + (size_t)blockIdx.y * NQ))[jp] = make_float2(acc0, acc1);
}

// ---------------- G = A^T A via bf16 MFMA (fp32 out) ----------------
// Bm = Atu (2048 rows x 4096 bf16, k-contiguous). C = Bm . Bm^T.
// 128x128 tile/block, 4 waves, each 64x64 (4x4 MFMA 16x16x32 tiles).
__global__ __launch_bounds__(256) void k_gram(const unsigned* __restrict__ Bm,
                                              float* __restrict__ G) {
  __shared__ unsigned As[128 * 20];  // stride 20 uints (80 B): 16B-aligned, <=2-way bank alias
  __shared__ unsigned Bs[128 * 20];
  const int i0 = blockIdx.x * 128, j0 = blockIdx.y * 128;
  const int tid = threadIdx.x;
  const int w = tid >> 6, lane = tid & 63;
  const int wr = (w >> 1) * 64, wc = (w & 1) * 64;
  const int srow = tid >> 1, suo = (tid & 1) * 8;
  const int frow = lane & 15, fqo = (lane >> 4) * 4;

  f32x4 acc[4][4];
#pragma unroll
  for (int a = 0; a < 4; ++a)
#pragma unroll
    for (int b = 0; b < 4; ++b) {
      acc[a][b][0] = 0.f; acc[a][b][1] = 0.f;
      acc[a][b][2] = 0.f; acc[a][b][3] = 0.f;
    }

  for (int ks = 0; ks < 128; ++ks) {
    int ku = ks * 16;
    const unsigned* pa = Bm + (size_t)(i0 + srow) * 2048 + ku + suo;
    const unsigned* pb = Bm + (size_t)(j0 + srow) * 2048 + ku + suo;
    uint4 a0 = *(const uint4*)pa;
    uint4 a1 = *(const uint4*)(pa + 4);
    uint4 b0 = *(const uint4*)pb;
    uint4 b1 = *(const uint4*)(pb + 4);
    __syncthreads();
    *(uint4*)(As + srow * 20 + suo) = a0;
    *(uint4*)(As + srow * 20 + suo + 4) = a1;
    *(uint4*)(Bs + srow * 20 + suo) = b0;
    *(uint4*)(Bs + srow * 20 + suo + 4) = b1;
    __syncthreads();
    short8 af[4], bf[4];
#pragma unroll
    for (int a = 0; a < 4; ++a)
      af[a] = *(const short8*)(As + (wr + a * 16 + frow) * 20 + fqo);
#pragma unroll
    for (int b = 0; b < 4; ++b)
      bf[b] = *(const short8*)(Bs + (wc + b * 16 + frow) * 20 + fqo);
#pragma unroll
    for (int a = 0; a < 4; ++a)
#pragma unroll
      for (int b = 0; b < 4; ++b)
        acc[a][b] = __builtin_amdgcn_mfma_f32_16x16x32_bf16(af[a], bf[b], acc[a][b], 0, 0, 0);
  }
  // C/D layout: col = lane&15, row = (lane>>4)*4 + reg
  const int q4 = lane >> 4, c16 = lane & 15;
#pragma unroll
  for (int a = 0; a < 4; ++a)
#pragma unroll
    for (int b = 0; b < 4; ++b)
#pragma unroll
      for (int r = 0; r < 4; ++r) {
        int gr = i0 + wr + a * 16 + q4 * 4 + r;
        int gc = j0 + wc + b * 16 + c16;
        G[(size_t)gr * NQ + gc] = acc[a][b][r];
      }
}

// q, r0 = rhs
__global__ __launch_bounds__(256) void k_qrhs(const float* __restrict__ h2,
    const int* __restrict__ feat_ids, const float* __restrict__ x_prior,
    const float* __restrict__ btA_parts, float* __restrict__ q, float* __restrict__ r) {
  int j = blockIdx.x * 256 + threadIdx.x;
  int f = feat_ids[j];
  float hf = h2[f] + 1e-5f;
  q[j] = hf;
  float bta = 0.f;
#pragma unroll
  for (int c = 0; c < 32; ++c) bta += btA_parts[(size_t)c * NQ + j];
  r[j] = x_prior[j] * hf + bta;  // rhs = -p
}

__global__ __launch_bounds__(256) void k_qdiag(const float* __restrict__ q, float* __restrict__ G) {
  int j = blockIdx.x * 256 + threadIdx.x;
  G[(size_t)j * NQ + j] += q[j];
}

// ---------------- CG: ONE kernel/iter.  Qp = G p (q folded into G diag) ---
// 512 blocks x 256 threads. Each block redundantly computes scalars via
// block reduction (thread owns 8 elems); updated p assembled in LDS;
// each wave then computes one row of G.p. Block 0 persists p/r/x.
__global__ __launch_bounds__(256) void k_cgG(int k, const float* __restrict__ G,
    const float* __restrict__ r_old, float* __restrict__ r_new,
    const float* __restrict__ p_old, float* __restrict__ p_new,
    const float* __restrict__ Qp_in, float* __restrict__ Qp_out,
    float* __restrict__ xcg) {
  __shared__ float pshare[NQ];
  __shared__ float lds[4];
  const int tid = threadIdx.x, bid = blockIdx.x;
  const float4* r4 = (const float4*)r_old;
  float4 ra = r4[tid * 2], rb2 = r4[tid * 2 + 1];
  float pv[8];
  if (k == 0) {
    pv[0] = ra.x; pv[1] = ra.y; pv[2] = ra.z; pv[3] = ra.w;
    pv[4] = rb2.x; pv[5] = rb2.y; pv[6] = rb2.z; pv[7] = rb2.w;
    if (bid == 0) {
      ((float4*)p_new)[tid * 2] = ra;
      ((float4*)p_new)[tid * 2 + 1] = rb2;
    }
  } else {
    const float4* p4 = (const float4*)p_old;
    const float4* qp4 = (const float4*)Qp_in;
    float4 pa = p4[tid * 2], pb = p4[tid * 2 + 1];
    float4 qa = qp4[tid * 2], qb = qp4[tid * 2 + 1];
    float rr = ra.x * ra.x + ra.y * ra.y + ra.z * ra.z + ra.w * ra.w +
               rb2.x * rb2.x + rb2.y * rb2.y + rb2.z * rb2.z + rb2.w * rb2.w;
    float pap = pa.x * qa.x + pa.y * qa.y + pa.z * qa.z + pa.w * qa.w +
                pb.x * qb.x + pb.y * qb.y + pb.z * qb.z + pb.w * qb.w;
    rr = bred256(rr, lds);
    pap = bred256(pap, lds);
    float alpha = rr / pap;
    if (bid == 0) {
      float4* x4 = (float4*)xcg;
      float4 xa = x4[tid * 2], xb = x4[tid * 2 + 1];
      xa.x += alpha * pa.x; xa.y += alpha * pa.y;
      xa.z += alpha * pa.z; xa.w += alpha * pa.w;
      xb.x += alpha * pb.x; xb.y += alpha * pb.y;
      xb.z += alpha * pb.z; xb.w += alpha * pb.w;
      x4[tid * 2] = xa; x4[tid * 2 + 1] = xb;
    }
    ra.x -= alpha * qa.x; ra.y -= alpha * qa.y;
    ra.z -= alpha * qa.z; ra.w -= alpha * qa.w;
    rb2.x -= alpha * qb.x; rb2.y -= alpha * qb.y;
    rb2.z -= alpha * qb.z; rb2.w -= alpha * qb.w;
    float rrn = ra.x * ra.x + ra.y * ra.y + ra.z * ra.z + ra.w * ra.w +
                rb2.x * rb2.x + rb2.y * rb2.y + rb2.z * rb2.z + rb2.w * rb2.w;
    rrn = bred256(rrn, lds);
    float beta = rrn / rr;
    pv[0] = ra.x + beta * pa.x; pv[1] = ra.y + beta * pa.y;
    pv[2] = ra.z + beta * pa.z; pv[3] = ra.w + beta * pa.w;
    pv[4] = rb2.x + beta * pb.x; pv[5] = rb2.y + beta * pb.y;
    pv[6] = rb2.z + beta * pb.z; pv[7] = rb2.w + beta * pb.w;
    if (bid == 0) {
      ((float4*)r_new)[tid * 2] = ra;
      ((float4*)r_new)[tid * 2 + 1] = rb2;
      ((float4*)p_new)[tid * 2] = make_float4(pv[0], pv[1], pv[2], pv[3]);
      ((float4*)p_new)[tid * 2 + 1] = make_float4(pv[4], pv[5], pv[6], pv[7]);
    }
  }
  ((float4*)pshare)[tid * 2] = make_float4(pv[0], pv[1], pv[2], pv[3]);
  ((float4*)pshare)[tid * 2 + 1] = make_float4(pv[4], pv[5], pv[6], pv[7]);
  __syncthreads();
  // matvec: one G-row per wave
  const int w = tid >> 6, lane = tid & 63;
  const int row = bid * 4 + w;
  const float4* Gr = (const float4*)(G + (size_t)row * NQ);
  const float4* ps4 = (const float4*)pshare;
  float acc = 0.f;
#pragma unroll
  for (int c = 0; c < 4; ++c) {
#pragma unroll
    for (int hh = 0; hh < 2; ++hh) {
      int idx = c * 128 + lane * 2 + hh;
      float4 g = Gr[idx];
      float4 pp = ps4[idx];
      acc += g.x * pp.x + g.y * pp.y + g.z * pp.z + g.w * pp.w;
    }
  }
  acc = wred(acc);
  if (lane == 0) Qp_out[row] = acc;
}

// ---------------- final: alpha + out = x + alpha p -----------------------
__global__ __launch_bounds__(256) void k_cgfin(const float* __restrict__ r_last,
    const float* __restrict__ p_last, const float* __restrict__ Qp,
    const float* __restrict__ xcg, float* __restrict__ out) {
  const int tid = threadIdx.x;
  const int lane = tid & 63;
  const float4* r4 = (const float4*)r_last;
  const float4* p4 = (const float4*)p_last;
  const float4* q4 = (const float4*)Qp;
  float rr = 0.f, pap = 0.f;
#pragma unroll
  for (int c = 0; c < 4; ++c) {
#pragma unroll
    for (int hh = 0; hh < 2; ++hh) {
      float4 rv = r4[c * 128 + lane * 2 + hh];
      float4 pv = p4[c * 128 + lane * 2 + hh];
      float4 qv = q4[c * 128 + lane * 2 + hh];
      rr += rv.x * rv.x + rv.y * rv.y + rv.z * rv.z + rv.w * rv.w;
      pap += pv.x * qv.x + pv.y * qv.y + pv.z * qv.z + pv.w * qv.w;
    }
  }
  rr = wred(rr);
  pap = wred(pap);
  float alpha = rr / pap;
  const float4* x4 = (const float4*)xcg;
  float4* o4 = (float4*)out;
#pragma unroll
  for (int hh = 0; hh < 2; ++hh) {
    int i4 = tid * 2 + hh;
    float4 xv = x4[i4];
    float4 pv = p4[i4];
    xv.x += alpha * pv.x; xv.y += alpha * pv.y;
    xv.z += alpha * pv.z; xv.w += alpha * pv.w;
    o4[i4] = xv;
  }
}

// ---------------- launch ----------------

extern "C" void kernel_launch(void* const* d_in, const int* in_sizes, int n_in,
                              void* d_out, int out_size, void* d_ws, size_t ws_size,
                              hipStream_t stream) {
  const float* x      = (const float*)d_in[0];
  const int*   ei     = (const int*)d_in[1];
  const float* A      = (const float*)d_in[2];
  const float* b      = (const float*)d_in[3];
  const int*   fids   = (const int*)d_in[4];
  const float* xprior = (const float*)d_in[5];
  const float* lamb   = (const float*)d_in[6];
  const float* W10    = (const float*)d_in[7];
  const float* W11    = (const float*)d_in[8];
  const float* b1     = (const float*)d_in[9];
  const float* W20    = (const float*)d_in[10];
  const float* W21    = (const float*)d_in[11];
  const float* b2     = (const float*)d_in[12];
  float* out = (float*)d_out;

  char* base = (char*)d_ws;
  size_t o = 0;
  auto alloc = [&](size_t bytes) { size_t r = o; o = (o + bytes + 255) & ~size_t(255); return r; };

  // zero-init region (deg, cursor, xcg, t, s)
  size_t off_deg    = alloc(N_NODES * 4);
  size_t off_cursor = alloc(N_NODES * 4);
  size_t off_xcg    = alloc(NQ * 4);
  size_t off_t      = alloc(N_NODES * 4);
  size_t off_s      = alloc(N_NODES * 4);
  size_t zero_end   = o;
  size_t off_rowst  = alloc((N_NODES + 1) * 4);
  size_t off_dinv   = alloc(N_NODES * 4);
  size_t off_h2     = alloc(N_NODES * 4);
  size_t off_q      = alloc(NQ * 4);
  size_t off_r0     = alloc(NQ * 4);
  size_t off_r1     = alloc(NQ * 4);
  size_t off_p0     = alloc(NQ * 4);
  size_t off_p1     = alloc(NQ * 4);
  size_t off_Qp0    = alloc(NQ * 4);
  size_t off_Qp1    = alloc(NQ * 4);
  size_t off_btAp   = alloc(32 * NQ * 4);
  // union: {cols, wvals, msg1} (GNN phase) vs Atu (QP phase, after k_h2)
  size_t union_sz_gnn = 2 * ((size_t)N_EDGES * 4 + 256) + (size_t)N_NODES * F_DIM * 4;
  size_t union_sz_at  = (size_t)M_ROWS * NQ * 2;
  size_t off_union  = alloc(union_sz_gnn > union_sz_at ? union_sz_gnn : union_sz_at);
  size_t off_G      = alloc((size_t)NQ * NQ * 4);
  if (o > ws_size) return;

  int*   deg      = (int*)(base + off_deg);
  int*   cursor   = (int*)(base + off_cursor);
  float* xcg      = (float*)(base + off_xcg);
  float* t        = (float*)(base + off_t);
  float* s        = (float*)(base + off_s);
  int*   rowstart = (int*)(base + off_rowst);
  float* dinv     = (float*)(base + off_dinv);
  float* h2       = (float*)(base + off_h2);
  float* q        = (float*)(base + off_q);
  float* rb[2]    = {(float*)(base + off_r0), (float*)(base + off_r1)};
  float* pg[2]    = {(float*)(base + off_p0), (float*)(base + off_p1)};
  float* Qpb[2]   = {(float*)(base + off_Qp0), (float*)(base + off_Qp1)};
  float* btA_parts = (float*)(base + off_btAp);
  int*   cols     = (int*)(base + off_union);
  float* wvals    = (float*)(base + off_union + (size_t)N_EDGES * 4 + 256);
  float* msg1     = (float*)(base + off_union + 2 * ((size_t)N_EDGES * 4 + 256));
  unsigned* Atu   = (unsigned*)(base + off_union);
  float* G        = (float*)(base + off_G);

  hipMemsetAsync(d_ws, 0, zero_end, stream);

  // CSR build
  k_deg<<<(N_EDGES + 255) / 256, 256, 0, stream>>>(ei, deg);
  k_scan<<<1, 1024, 0, stream>>>(deg, rowstart, dinv);
  k_scatter<<<(N_EDGES + 255) / 256, 256, 0, stream>>>(ei, rowstart, cursor, dinv, cols, wvals);

  // GNN
  k_msg1<<<N_NODES / 4, 256, 0, stream>>>(x, rowstart, cols, wvals, msg1);
  k_gemm1<<<dim3((N_NODES + 63) / 64, H_DIM / 64), 256, 0, stream>>>(
      x, msg1, W10, W11, b1, W20, W21, t, s);
  k_h2<<<(N_NODES + 255) / 256, 256, 0, stream>>>(t, s, rowstart, cols, wvals, lamb, b2, h2);

  // QP setup (after k_h2: Atu overwrites cols/wvals/msg1)
  k_prep<<<dim3(4, 32), 256, 0, stream>>>(A, b, Atu, btA_parts);
  k_gram<<<dim3(16, 16), 256, 0, stream>>>(Atu, G);
  k_qrhs<<<NQ / 256, 256, 0, stream>>>(h2, fids, xprior, btA_parts, q, rb[0]);
  k_qdiag<<<NQ / 256, 256, 0, stream>>>(q, G);

  // CG: 1 kernel/iter
  k_cgG<<<512, 256, 0, stream>>>(0, G, rb[0], rb[0], pg[0], pg[0], Qpb[1], Qpb[0], xcg);
  for (int k = 1; k < NIT; ++k) {
    k_cgG<<<512, 256, 0, stream>>>(k, G, rb[(k - 1) & 1], rb[k & 1],
                                   pg[(k - 1) & 1], pg[k & 1],
                                   Qpb[(k - 1) & 1], Qpb[k & 1], xcg);
  }
  k_cgfin<<<1, 256, 0, stream>>>(rb[(NIT - 1) & 1], pg[(NIT - 1) & 1],
                                 Qpb[(NIT - 1) & 1], xcg, out);
}

// Round 6
// 482.433 us; speedup vs baseline: 6.4758x; 1.0857x over previous
//
#include <hip/hip_runtime.h>

#define N_NODES 20000
#define N_EDGES 320000
#define F_DIM   128
#define H_DIM   256
#define M_ROWS  4096
#define NQ      2048
#define NIT     24

typedef __attribute__((ext_vector_type(8))) short short8;   // 8 bf16 (4 VGPRs)
typedef __attribute__((ext_vector_type(4))) float f32x4;    // MFMA C/D

// ---------------- helpers ----------------

__device__ __forceinline__ float wred(float v) {
#pragma unroll
  for (int m = 32; m > 0; m >>= 1) v += __shfl_xor(v, m, 64);
  return v;
}

__device__ __forceinline__ float bred256(float v, float* lds) {
  v = wred(v);
  int w = threadIdx.x >> 6;
  if ((threadIdx.x & 63) == 0) lds[w] = v;
  __syncthreads();
  float tot = lds[0] + lds[1] + lds[2] + lds[3];
  __syncthreads();
  return tot;
}

__device__ __forceinline__ unsigned f2bf(float f) {
  unsigned u = __float_as_uint(f);
  unsigned r = u + 0x7fffu + ((u >> 16) & 1u);
  return r >> 16;
}

// ---------------- CSR build ----------------

__global__ __launch_bounds__(256) void k_deg(const int* __restrict__ ei, int* __restrict__ deg) {
  int e = blockIdx.x * 256 + threadIdx.x;
  if (e < N_EDGES) atomicAdd(&deg[ei[e]], 1);
}

__global__ __launch_bounds__(1024) void k_scan(const int* __restrict__ deg,
    int* __restrict__ rowstart, float* __restrict__ dinv) {
  __shared__ int part[1024];
  int t = threadIdx.x;
  const int chunk = (N_NODES + 1023) / 1024;  // 20
  int lo = t * chunk;
  int hi = lo + chunk; if (hi > N_NODES) hi = N_NODES;
  int s = 0;
  for (int i = lo; i < hi; ++i) {
    int d = deg[i];
    dinv[i] = d > 0 ? rsqrtf((float)d) : 0.f;
    s += d;
  }
  part[t] = s;
  __syncthreads();
  for (int off = 1; off < 1024; off <<= 1) {
    int v = part[t];
    int add = (t >= off) ? part[t - off] : 0;
    __syncthreads();
    part[t] = v + add;
    __syncthreads();
  }
  int base = (t > 0) ? part[t - 1] : 0;
  for (int i = lo; i < hi; ++i) { rowstart[i] = base; base += deg[i]; }
  if (t == 0) rowstart[N_NODES] = part[1023];
}

__global__ __launch_bounds__(256) void k_scatter(const int* __restrict__ ei,
    const int* __restrict__ rowstart, int* __restrict__ cursor,
    const float* __restrict__ dinv, int* __restrict__ cols, float* __restrict__ wvals) {
  int e = blockIdx.x * 256 + threadIdx.x;
  if (e >= N_EDGES) return;
  int r = ei[e];
  int c = ei[N_EDGES + e];
  int pos = rowstart[r] + atomicAdd(&cursor[r], 1);
  cols[pos] = c;
  wvals[pos] = -dinv[r] * dinv[c];
}

// ---------------- GNN layer 1 ----------------

__global__ __launch_bounds__(256) void k_msg1(const float* __restrict__ x,
    const int* __restrict__ rowstart, const int* __restrict__ cols,
    const float* __restrict__ wvals, float* __restrict__ msg) {
  int wid = (blockIdx.x * 256 + threadIdx.x) >> 6;
  int lane = threadIdx.x & 63;
  if (wid >= N_NODES) return;
  int s0 = rowstart[wid], s1 = rowstart[wid + 1];
  const float2* x2 = (const float2*)x;
  float2 acc = make_float2(0.f, 0.f);
  for (int e = s0; e < s1; ++e) {
    int c = cols[e];
    float w = wvals[e];
    float2 xv = x2[(size_t)c * 64 + lane];
    acc.x += w * xv.x;
    acc.y += w * xv.y;
  }
  ((float2*)msg)[(size_t)wid * 64 + lane] = acc;
}

// h = relu(x@W10 + msg@W11 + b1); fused projection t += h.W20, s += h.W21
__global__ __launch_bounds__(256) void k_gemm1(const float* __restrict__ x,
    const float* __restrict__ msg, const float* __restrict__ W10,
    const float* __restrict__ W11, const float* __restrict__ b1,
    const float* __restrict__ W20, const float* __restrict__ W21,
    float* __restrict__ t, float* __restrict__ s) {
  __shared__ float As[32][68];
  __shared__ float Bs[32][68];
  const int row0 = blockIdx.x * 64;
  const int col0 = blockIdx.y * 64;
  const int tid = threadIdx.x;
  const int tx = tid & 15, ty = tid >> 4;
  float acc[4][4] = {};
  for (int pass = 0; pass < 2; ++pass) {
    const float* Am = pass ? msg : x;
    const float* Bm = pass ? W11 : W10;
    for (int k0 = 0; k0 < F_DIM; k0 += 32) {
#pragma unroll
      for (int e = 0; e < 8; ++e) {
        int idx = tid + e * 256;
        int i = idx >> 5, kk = idx & 31;
        int gr = row0 + i;
        As[kk][i] = (gr < N_NODES) ? Am[(size_t)gr * F_DIM + k0 + kk] : 0.f;
      }
#pragma unroll
      for (int e = 0; e < 8; ++e) {
        int idx = tid + e * 256;
        int kk = idx >> 6, j = idx & 63;
        Bs[kk][j] = Bm[(size_t)(k0 + kk) * H_DIM + col0 + j];
      }
      __syncthreads();
#pragma unroll
      for (int kk = 0; kk < 32; ++kk) {
        float4 a = *(const float4*)&As[kk][ty * 4];
        float4 b = *(const float4*)&Bs[kk][tx * 4];
        float av[4] = {a.x, a.y, a.z, a.w};
        float bv[4] = {b.x, b.y, b.z, b.w};
#pragma unroll
        for (int ii = 0; ii < 4; ++ii)
#pragma unroll
          for (int jj = 0; jj < 4; ++jj) acc[ii][jj] += av[ii] * bv[jj];
      }
      __syncthreads();
    }
  }
#pragma unroll
  for (int ii = 0; ii < 4; ++ii) {
    int gr = row0 + ty * 4 + ii;
    float tp = 0.f, sp = 0.f;
#pragma unroll
    for (int jj = 0; jj < 4; ++jj) {
      int c = col0 + tx * 4 + jj;
      float val = acc[ii][jj] + b1[c];
      val = val > 0.f ? val : 0.f;
      tp += val * W20[c];
      sp += val * W21[c];
    }
#pragma unroll
    for (int m = 1; m < 16; m <<= 1) {
      tp += __shfl_xor(tp, m, 64);
      sp += __shfl_xor(sp, m, 64);
    }
    if (tx == 0 && gr < N_NODES) {
      atomicAdd(&t[gr], tp);
      atomicAdd(&s[gr], sp);
    }
  }
}

// ---------------- GNN layer 2 scalar gather ----------------

__global__ __launch_bounds__(256) void k_h2(const float* __restrict__ t,
    const float* __restrict__ s, const int* __restrict__ rowstart,
    const int* __restrict__ cols, const float* __restrict__ wvals,
    const float* __restrict__ lamb, const float* __restrict__ b2, float* __restrict__ h2) {
  int i = blockIdx.x * 256 + threadIdx.x;
  if (i >= N_NODES) return;
  float m = 0.f;
  int s0 = rowstart[i], s1 = rowstart[i + 1];
  for (int e = s0; e < s1; ++e) m += wvals[e] * s[cols[e]];
  float val = t[i] + m + b2[0];
  val = val > 0.f ? val : 0.f;
  h2[i] = lamb[0] * val;
}

// ---------------- QP setup: bf16 A^T + b^T A partials ----------------
// Atu: row j (0..2047) = column j of A, 4096 bf16 packed in 2048 uints.
__global__ __launch_bounds__(256) void k_prep(const float* __restrict__ A,
    const float* __restrict__ b, unsigned* __restrict__ Atu, float* __restrict__ btA_parts) {
  int jp = blockIdx.x * 256 + threadIdx.x;   // 0..1023 col pairs
  int k0 = blockIdx.y * 128;
  const float2* A2 = (const float2*)A;
  float acc0 = 0.f, acc1 = 0.f;
  for (int kk = 0; kk < 128; kk += 8) {
    float ax[8], ay[8];
#pragma unroll
    for (int i = 0; i < 8; ++i) {
      int k = k0 + kk + i;
      float2 a = A2[(size_t)k * 1024 + jp];
      float bk = b[k];
      acc0 += a.x * bk;
      acc1 += a.y * bk;
      ax[i] = a.x; ay[i] = a.y;
    }
    uint4 t0, t1;
    t0.x = f2bf(ax[0]) | (f2bf(ax[1]) << 16);
    t0.y = f2bf(ax[2]) | (f2bf(ax[3]) << 16);
    t0.z = f2bf(ax[4]) | (f2bf(ax[5]) << 16);
    t0.w = f2bf(ax[6]) | (f2bf(ax[7]) << 16);
    t1.x = f2bf(ay[0]) | (f2bf(ay[1]) << 16);
    t1.y = f2bf(ay[2]) | (f2bf(ay[3]) << 16);
    t1.z = f2bf(ay[4]) | (f2bf(ay[5]) << 16);
    t1.w = f2bf(ay[6]) | (f2bf(ay[7]) << 16);
    int uoff = (k0 + kk) >> 1;
    *(uint4*)(Atu + (size_t)(2 * jp) * 2048 + uoff) = t0;
    *(uint4*)(Atu + (size_t)(2 * jp + 1) * 2048 + uoff) = t1;
  }
  ((float2*)(btA_parts + (size_t)blockIdx.y * NQ))[jp] = make_float2(acc0, acc1);
}

// q, r0 = rhs
__global__ __launch_bounds__(256) void k_qrhs(const float* __restrict__ h2,
    const int* __restrict__ feat_ids, const float* __restrict__ x_prior,
    const float* __restrict__ btA_parts, float* __restrict__ q, float* __restrict__ r) {
  int j = blockIdx.x * 256 + threadIdx.x;
  int f = feat_ids[j];
  float hf = h2[f] + 1e-5f;
  q[j] = hf;
  float bta = 0.f;
#pragma unroll
  for (int c = 0; c < 32; ++c) bta += btA_parts[(size_t)c * NQ + j];
  r[j] = x_prior[j] * hf + bta;  // rhs = -p
}

// ---------------- G = A^T A + diag(q) via bf16 MFMA (fp32 out) ----------
// Bm = Atu (2048 rows x 4096 bf16, k-contiguous). C = Bm . Bm^T.
// 128x128 tile/block, 4 waves each 64x64 (4x4 MFMA 16x16x32 tiles).
// Double-buffered LDS + one-iteration-ahead register prefetch, ONE barrier
// per K-iter (dbuf makes the single barrier sufficient: writes to buf b at
// iter ks happen only after all waves passed barrier(ks-1), which is after
// their reads of buf b at iter ks-2 completed).
#define GR_ST 20  // staged row stride in uints (16 data + 4 pad), 80 B, 16B-aligned

__global__ __launch_bounds__(256) void k_gram(const unsigned* __restrict__ Bm,
                                              const float* __restrict__ q,
                                              float* __restrict__ G) {
  __shared__ unsigned As[2][128 * GR_ST];
  __shared__ unsigned Bs[2][128 * GR_ST];
  const int i0 = blockIdx.x * 128, j0 = blockIdx.y * 128;
  const int tid = threadIdx.x;
  const int w = tid >> 6, lane = tid & 63;
  const int wr = (w >> 1) * 64, wc = (w & 1) * 64;
  const int srow = tid >> 1, suo = (tid & 1) * 8;
  const int frow = lane & 15, fqo = (lane >> 4) * 4;

  f32x4 acc[4][4];
#pragma unroll
  for (int a = 0; a < 4; ++a)
#pragma unroll
    for (int b = 0; b < 4; ++b) {
      acc[a][b][0] = 0.f; acc[a][b][1] = 0.f;
      acc[a][b][2] = 0.f; acc[a][b][3] = 0.f;
    }

  const unsigned* pa_base = Bm + (size_t)(i0 + srow) * 2048 + suo;
  const unsigned* pb_base = Bm + (size_t)(j0 + srow) * 2048 + suo;

  // prefetch ks=0
  uint4 ra0 = *(const uint4*)(pa_base);
  uint4 ra1 = *(const uint4*)(pa_base + 4);
  uint4 rb0 = *(const uint4*)(pb_base);
  uint4 rb1 = *(const uint4*)(pb_base + 4);

  for (int ks = 0; ks < 128; ++ks) {
    const int b = ks & 1;
    unsigned* as = As[b] + srow * GR_ST + suo;
    unsigned* bs = Bs[b] + srow * GR_ST + suo;
    *(uint4*)as = ra0; *(uint4*)(as + 4) = ra1;
    *(uint4*)bs = rb0; *(uint4*)(bs + 4) = rb1;
    if (ks + 1 < 128) {
      const int ku = (ks + 1) * 16;
      ra0 = *(const uint4*)(pa_base + ku);
      ra1 = *(const uint4*)(pa_base + ku + 4);
      rb0 = *(const uint4*)(pb_base + ku);
      rb1 = *(const uint4*)(pb_base + ku + 4);
    }
    __syncthreads();
    short8 af[4], bf[4];
#pragma unroll
    for (int a = 0; a < 4; ++a)
      af[a] = *(const short8*)(As[b] + (wr + a * 16 + frow) * GR_ST + fqo);
#pragma unroll
    for (int b2 = 0; b2 < 4; ++b2)
      bf[b2] = *(const short8*)(Bs[b] + (wc + b2 * 16 + frow) * GR_ST + fqo);
#pragma unroll
    for (int a = 0; a < 4; ++a)
#pragma unroll
      for (int b2 = 0; b2 < 4; ++b2)
        acc[a][b2] = __builtin_amdgcn_mfma_f32_16x16x32_bf16(af[a], bf[b2], acc[a][b2], 0, 0, 0);
  }
  // C/D layout: col = lane&15, row = (lane>>4)*4 + reg ; fold diag(q) in.
  const int q4 = lane >> 4, c16 = lane & 15;
#pragma unroll
  for (int a = 0; a < 4; ++a)
#pragma unroll
    for (int b2 = 0; b2 < 4; ++b2)
#pragma unroll
      for (int r = 0; r < 4; ++r) {
        int gr = i0 + wr + a * 16 + q4 * 4 + r;
        int gc = j0 + wc + b2 * 16 + c16;
        float val = acc[a][b2][r];
        if (gr == gc) val += q[gr];
        G[(size_t)gr * NQ + gc] = val;
      }
}

// ---------------- CG: ONE kernel/iter.  Qp = G p (q folded into G diag) ---
__global__ __launch_bounds__(256) void k_cgG(int k, const float* __restrict__ G,
    const float* __restrict__ r_old, float* __restrict__ r_new,
    const float* __restrict__ p_old, float* __restrict__ p_new,
    const float* __restrict__ Qp_in, float* __restrict__ Qp_out,
    float* __restrict__ xcg) {
  __shared__ float pshare[NQ];
  __shared__ float lds[4];
  const int tid = threadIdx.x, bid = blockIdx.x;
  const float4* r4 = (const float4*)r_old;
  float4 ra = r4[tid * 2], rb2 = r4[tid * 2 + 1];
  float pv[8];
  if (k == 0) {
    pv[0] = ra.x; pv[1] = ra.y; pv[2] = ra.z; pv[3] = ra.w;
    pv[4] = rb2.x; pv[5] = rb2.y; pv[6] = rb2.z; pv[7] = rb2.w;
    if (bid == 0) {
      ((float4*)p_new)[tid * 2] = ra;
      ((float4*)p_new)[tid * 2 + 1] = rb2;
    }
  } else {
    const float4* p4 = (const float4*)p_old;
    const float4* qp4 = (const float4*)Qp_in;
    float4 pa = p4[tid * 2], pb = p4[tid * 2 + 1];
    float4 qa = qp4[tid * 2], qb = qp4[tid * 2 + 1];
    float rr = ra.x * ra.x + ra.y * ra.y + ra.z * ra.z + ra.w * ra.w +
               rb2.x * rb2.x + rb2.y * rb2.y + rb2.z * rb2.z + rb2.w * rb2.w;
    float pap = pa.x * qa.x + pa.y * qa.y + pa.z * qa.z + pa.w * qa.w +
                pb.x * qb.x + pb.y * qb.y + pb.z * qb.z + pb.w * qb.w;
    rr = bred256(rr, lds);
    pap = bred256(pap, lds);
    float alpha = rr / pap;
    if (bid == 0) {
      float4* x4 = (float4*)xcg;
      float4 xa = x4[tid * 2], xb = x4[tid * 2 + 1];
      xa.x += alpha * pa.x; xa.y += alpha * pa.y;
      xa.z += alpha * pa.z; xa.w += alpha * pa.w;
      xb.x += alpha * pb.x; xb.y += alpha * pb.y;
      xb.z += alpha * pb.z; xb.w += alpha * pb.w;
      x4[tid * 2] = xa; x4[tid * 2 + 1] = xb;
    }
    ra.x -= alpha * qa.x; ra.y -= alpha * qa.y;
    ra.z -= alpha * qa.z; ra.w -= alpha * qa.w;
    rb2.x -= alpha * qb.x; rb2.y -= alpha * qb.y;
    rb2.z -= alpha * qb.z; rb2.w -= alpha * qb.w;
    float rrn = ra.x * ra.x + ra.y * ra.y + ra.z * ra.z + ra.w * ra.w +
                rb2.x * rb2.x + rb2.y * rb2.y + rb2.z * rb2.z + rb2.w * rb2.w;
    rrn = bred256(rrn, lds);
    float beta = rrn / rr;
    pv[0] = ra.x + beta * pa.x; pv[1] = ra.y + beta * pa.y;
    pv[2] = ra.z + beta * pa.z; pv[3] = ra.w + beta * pa.w;
    pv[4] = rb2.x + beta * pb.x; pv[5] = rb2.y + beta * pb.y;
    pv[6] = rb2.z + beta * pb.z; pv[7] = rb2.w + beta * pb.w;
    if (bid == 0) {
      ((float4*)r_new)[tid * 2] = ra;
      ((float4*)r_new)[tid * 2 + 1] = rb2;
      ((float4*)p_new)[tid * 2] = make_float4(pv[0], pv[1], pv[2], pv[3]);
      ((float4*)p_new)[tid * 2 + 1] = make_float4(pv[4], pv[5], pv[6], pv[7]);
    }
  }
  ((float4*)pshare)[tid * 2] = make_float4(pv[0], pv[1], pv[2], pv[3]);
  ((float4*)pshare)[tid * 2 + 1] = make_float4(pv[4], pv[5], pv[6], pv[7]);
  __syncthreads();
  // matvec: one G-row per wave
  const int w = tid >> 6, lane = tid & 63;
  const int row = bid * 4 + w;
  const float4* Gr = (const float4*)(G + (size_t)row * NQ);
  const float4* ps4 = (const float4*)pshare;
  float acc = 0.f;
#pragma unroll
  for (int c = 0; c < 4; ++c) {
#pragma unroll
    for (int hh = 0; hh < 2; ++hh) {
      int idx = c * 128 + lane * 2 + hh;
      float4 g = Gr[idx];
      float4 pp = ps4[idx];
      acc += g.x * pp.x + g.y * pp.y + g.z * pp.z + g.w * pp.w;
    }
  }
  acc = wred(acc);
  if (lane == 0) Qp_out[row] = acc;
}

// ---------------- final: alpha + out = x + alpha p -----------------------
__global__ __launch_bounds__(256) void k_cgfin(const float* __restrict__ r_last,
    const float* __restrict__ p_last, const float* __restrict__ Qp,
    const float* __restrict__ xcg, float* __restrict__ out) {
  const int tid = threadIdx.x;
  const int lane = tid & 63;
  const float4* r4 = (const float4*)r_last;
  const float4* p4 = (const float4*)p_last;
  const float4* q4 = (const float4*)Qp;
  float rr = 0.f, pap = 0.f;
#pragma unroll
  for (int c = 0; c < 4; ++c) {
#pragma unroll
    for (int hh = 0; hh < 2; ++hh) {
      float4 rv = r4[c * 128 + lane * 2 + hh];
      float4 pv = p4[c * 128 + lane * 2 + hh];
      float4 qv = q4[c * 128 + lane * 2 + hh];
      rr += rv.x * rv.x + rv.y * rv.y + rv.z * rv.z + rv.w * rv.w;
      pap += pv.x * qv.x + pv.y * qv.y + pv.z * qv.z + pv.w * qv.w;
    }
  }
  rr = wred(rr);
  pap = wred(pap);
  float alpha = rr / pap;
  const float4* x4 = (const float4*)xcg;
  float4* o4 = (float4*)out;
#pragma unroll
  for (int hh = 0; hh < 2; ++hh) {
    int i4 = tid * 2 + hh;
    float4 xv = x4[i4];
    float4 pv = p4[i4];
    xv.x += alpha * pv.x; xv.y += alpha * pv.y;
    xv.z += alpha * pv.z; xv.w += alpha * pv.w;
    o4[i4] = xv;
  }
}

// ---------------- launch ----------------

extern "C" void kernel_launch(void* const* d_in, const int* in_sizes, int n_in,
                              void* d_out, int out_size, void* d_ws, size_t ws_size,
                              hipStream_t stream) {
  const float* x      = (const float*)d_in[0];
  const int*   ei     = (const int*)d_in[1];
  const float* A      = (const float*)d_in[2];
  const float* b      = (const float*)d_in[3];
  const int*   fids   = (const int*)d_in[4];
  const float* xprior = (const float*)d_in[5];
  const float* lamb   = (const float*)d_in[6];
  const float* W10    = (const float*)d_in[7];
  const float* W11    = (const float*)d_in[8];
  const float* b1     = (const float*)d_in[9];
  const float* W20    = (const float*)d_in[10];
  const float* W21    = (const float*)d_in[11];
  const float* b2     = (const float*)d_in[12];
  float* out = (float*)d_out;

  char* base = (char*)d_ws;
  size_t o = 0;
  auto alloc = [&](size_t bytes) { size_t r = o; o = (o + bytes + 255) & ~size_t(255); return r; };

  // zero-init region (deg, cursor, xcg, t, s)
  size_t off_deg    = alloc(N_NODES * 4);
  size_t off_cursor = alloc(N_NODES * 4);
  size_t off_xcg    = alloc(NQ * 4);
  size_t off_t      = alloc(N_NODES * 4);
  size_t off_s      = alloc(N_NODES * 4);
  size_t zero_end   = o;
  size_t off_rowst  = alloc((N_NODES + 1) * 4);
  size_t off_dinv   = alloc(N_NODES * 4);
  size_t off_h2     = alloc(N_NODES * 4);
  size_t off_q      = alloc(NQ * 4);
  size_t off_r0     = alloc(NQ * 4);
  size_t off_r1     = alloc(NQ * 4);
  size_t off_p0     = alloc(NQ * 4);
  size_t off_p1     = alloc(NQ * 4);
  size_t off_Qp0    = alloc(NQ * 4);
  size_t off_Qp1    = alloc(NQ * 4);
  size_t off_btAp   = alloc(32 * NQ * 4);
  // union: {cols, wvals, msg1} (GNN phase) vs Atu (QP phase, after k_h2)
  size_t union_sz_gnn = 2 * ((size_t)N_EDGES * 4 + 256) + (size_t)N_NODES * F_DIM * 4;
  size_t union_sz_at  = (size_t)M_ROWS * NQ * 2;
  size_t off_union  = alloc(union_sz_gnn > union_sz_at ? union_sz_gnn : union_sz_at);
  size_t off_G      = alloc((size_t)NQ * NQ * 4);
  if (o > ws_size) return;

  int*   deg      = (int*)(base + off_deg);
  int*   cursor   = (int*)(base + off_cursor);
  float* xcg      = (float*)(base + off_xcg);
  float* t        = (float*)(base + off_t);
  float* s        = (float*)(base + off_s);
  int*   rowstart = (int*)(base + off_rowst);
  float* dinv     = (float*)(base + off_dinv);
  float* h2       = (float*)(base + off_h2);
  float* q        = (float*)(base + off_q);
  float* rb[2]    = {(float*)(base + off_r0), (float*)(base + off_r1)};
  float* pg[2]    = {(float*)(base + off_p0), (float*)(base + off_p1)};
  float* Qpb[2]   = {(float*)(base + off_Qp0), (float*)(base + off_Qp1)};
  float* btA_parts = (float*)(base + off_btAp);
  int*   cols     = (int*)(base + off_union);
  float* wvals    = (float*)(base + off_union + (size_t)N_EDGES * 4 + 256);
  float* msg1     = (float*)(base + off_union + 2 * ((size_t)N_EDGES * 4 + 256));
  unsigned* Atu   = (unsigned*)(base + off_union);
  float* G        = (float*)(base + off_G);

  hipMemsetAsync(d_ws, 0, zero_end, stream);

  // CSR build
  k_deg<<<(N_EDGES + 255) / 256, 256, 0, stream>>>(ei, deg);
  k_scan<<<1, 1024, 0, stream>>>(deg, rowstart, dinv);
  k_scatter<<<(N_EDGES + 255) / 256, 256, 0, stream>>>(ei, rowstart, cursor, dinv, cols, wvals);

  // GNN
  k_msg1<<<N_NODES / 4, 256, 0, stream>>>(x, rowstart, cols, wvals, msg1);
  k_gemm1<<<dim3((N_NODES + 63) / 64, H_DIM / 64), 256, 0, stream>>>(
      x, msg1, W10, W11, b1, W20, W21, t, s);
  k_h2<<<(N_NODES + 255) / 256, 256, 0, stream>>>(t, s, rowstart, cols, wvals, lamb, b2, h2);

  // QP setup (after k_h2: Atu overwrites cols/wvals/msg1)
  k_prep<<<dim3(4, 32), 256, 0, stream>>>(A, b, Atu, btA_parts);
  k_qrhs<<<NQ / 256, 256, 0, stream>>>(h2, fids, xprior, btA_parts, q, rb[0]);
  k_gram<<<dim3(16, 16), 256, 0, stream>>>(Atu, q, G);

  // CG: 1 kernel/iter
  k_cgG<<<512, 256, 0, stream>>>(0, G, rb[0], rb[0], pg[0], pg[0], Qpb[1], Qpb[0], xcg);
  for (int k = 1; k < NIT; ++k) {
    k_cgG<<<512, 256, 0, stream>>>(k, G, rb[(k - 1) & 1], rb[k & 1],
                                   pg[(k - 1) & 1], pg[k & 1],
                                   Qpb[(k - 1) & 1], Qpb[k & 1], xcg);
  }
  k_cgfin<<<1, 256, 0, stream>>>(rb[(NIT - 1) & 1], pg[(NIT - 1) & 1],
                                 Qpb[(NIT - 1) & 1], xcg, out);
}

// Round 8
// 437.589 us; speedup vs baseline: 7.1394x; 1.1025x over previous
//
#include <hip/hip_runtime.h>

#define N_NODES 20000
#define N_EDGES 320000
#define F_DIM   128
#define H_DIM   256
#define M_ROWS  4096
#define NQ      2048
#define NIT     24
#define MM_ROWS 20032   // 313 * 64, padded row count for bf16 [x|msg]

typedef __attribute__((ext_vector_type(8))) short short8;   // 8 bf16 (4 VGPRs)
typedef __attribute__((ext_vector_type(4))) float f32x4;    // MFMA C/D

// ---------------- helpers ----------------

__device__ __forceinline__ float wred(float v) {
#pragma unroll
  for (int m = 32; m > 0; m >>= 1) v += __shfl_xor(v, m, 64);
  return v;
}

__device__ __forceinline__ float bred256(float v, float* lds) {
  v = wred(v);
  int w = threadIdx.x >> 6;
  if ((threadIdx.x & 63) == 0) lds[w] = v;
  __syncthreads();
  float tot = lds[0] + lds[1] + lds[2] + lds[3];
  __syncthreads();
  return tot;
}

__device__ __forceinline__ unsigned f2bf(float f) {
  unsigned u = __float_as_uint(f);
  unsigned r = u + 0x7fffu + ((u >> 16) & 1u);
  return r >> 16;
}

// ---------------- CSR build ----------------

__global__ __launch_bounds__(256) void k_deg(const int* __restrict__ ei, int* __restrict__ deg) {
  int e = blockIdx.x * 256 + threadIdx.x;
  if (e < N_EDGES) atomicAdd(&deg[ei[e]], 1);
}

__global__ __launch_bounds__(1024) void k_scan(const int* __restrict__ deg,
    int* __restrict__ rowstart, float* __restrict__ dinv) {
  __shared__ int part[1024];
  int t = threadIdx.x;
  const int chunk = (N_NODES + 1023) / 1024;  // 20
  int lo = t * chunk;
  int hi = lo + chunk; if (hi > N_NODES) hi = N_NODES;
  int s = 0;
  for (int i = lo; i < hi; ++i) {
    int d = deg[i];
    dinv[i] = d > 0 ? rsqrtf((float)d) : 0.f;
    s += d;
  }
  part[t] = s;
  __syncthreads();
  for (int off = 1; off < 1024; off <<= 1) {
    int v = part[t];
    int add = (t >= off) ? part[t - off] : 0;
    __syncthreads();
    part[t] = v + add;
    __syncthreads();
  }
  int base = (t > 0) ? part[t - 1] : 0;
  for (int i = lo; i < hi; ++i) { rowstart[i] = base; base += deg[i]; }
  if (t == 0) rowstart[N_NODES] = part[1023];
}

__global__ __launch_bounds__(256) void k_scatter(const int* __restrict__ ei,
    const int* __restrict__ rowstart, int* __restrict__ cursor,
    const float* __restrict__ dinv, int* __restrict__ cols, float* __restrict__ wvals) {
  int e = blockIdx.x * 256 + threadIdx.x;
  if (e >= N_EDGES) return;
  int r = ei[e];
  int c = ei[N_EDGES + e];
  int pos = rowstart[r] + atomicAdd(&cursor[r], 1);
  cols[pos] = c;
  wvals[pos] = -dinv[r] * dinv[c];
}

// ---------------- bf16 packing of [x | msg] ----------------
// xmsgb: MM_ROWS x 256 bf16 row-major. cols 0..127 = x (bf16), 128..255 = msg.
// This kernel fills the x half (+ zeros pad rows incl. msg half).
__global__ __launch_bounds__(256) void k_convx(const float* __restrict__ x,
                                               unsigned* __restrict__ xu) {
  int gid = blockIdx.x * 256 + threadIdx.x;   // MM_ROWS*16 threads
  int row = gid >> 4;
  int q8 = gid & 15;
  uint4* xu4 = (uint4*)xu;
  if (row < N_NODES) {
    const float4* x4 = (const float4*)x;
    float4 a = x4[(size_t)row * 32 + q8 * 2];
    float4 b = x4[(size_t)row * 32 + q8 * 2 + 1];
    uint4 u;
    u.x = f2bf(a.x) | (f2bf(a.y) << 16);
    u.y = f2bf(a.z) | (f2bf(a.w) << 16);
    u.z = f2bf(b.x) | (f2bf(b.y) << 16);
    u.w = f2bf(b.z) | (f2bf(b.w) << 16);
    xu4[(size_t)row * 32 + q8] = u;
  } else {
    uint4 z = make_uint4(0, 0, 0, 0);
    xu4[(size_t)row * 32 + q8] = z;
    xu4[(size_t)row * 32 + 16 + q8] = z;
  }
}

// msg into bf16 half of xmsgb directly (fp32 accumulate, bf16 store)
__global__ __launch_bounds__(256) void k_msg1(const float* __restrict__ x,
    const int* __restrict__ rowstart, const int* __restrict__ cols,
    const float* __restrict__ wvals, unsigned* __restrict__ xu) {
  int wid = (blockIdx.x * 256 + threadIdx.x) >> 6;
  int lane = threadIdx.x & 63;
  if (wid >= N_NODES) return;
  int s0 = rowstart[wid], s1 = rowstart[wid + 1];
  const float2* x2 = (const float2*)x;
  float2 acc = make_float2(0.f, 0.f);
  for (int e = s0; e < s1; ++e) {
    int c = cols[e];
    float w = wvals[e];
    float2 xv = x2[(size_t)c * 64 + lane];
    acc.x += w * xv.x;
    acc.y += w * xv.y;
  }
  xu[(size_t)wid * 128 + 64 + lane] = f2bf(acc.x) | (f2bf(acc.y) << 16);
}

// Wtb[n][k] = bf16( Wcat[k][n] ), n=0..255, k=0..255 (Wcat = [W10;W11]).
// Row = 256 bf16 = 128 uints. One thread per uint (32768 threads).
__global__ __launch_bounds__(256) void k_prepW(const float* __restrict__ W10,
    const float* __restrict__ W11, unsigned* __restrict__ Wtb) {
  int gid = blockIdx.x * 256 + threadIdx.x;   // 0..32767
  int n = gid >> 7;                            // 0..255
  int u = gid & 127;                           // uint index in row
  int k0 = u * 2;
  float v0 = (k0 < 128) ? W10[(size_t)k0 * H_DIM + n]
                        : W11[(size_t)(k0 - 128) * H_DIM + n];
  float v1 = (k0 + 1 < 128) ? W10[(size_t)(k0 + 1) * H_DIM + n]
                            : W11[(size_t)(k0 - 127) * H_DIM + n];
  Wtb[(size_t)n * 128 + u] = f2bf(v0) | (f2bf(v1) << 16);
}

// ---------------- GNN layer-1 GEMM via MFMA ----------------
// h = relu([x|msg] @ Wcat + b1), fused projection t += h.W20, s += h.W21.
// Block: 256 thr, 64 rows; 4 waves each cover 64 cols of H=256.
// B-slices (256 n x 32 k bf16) double-buffered in LDS; A-frags from global.
#define WS_ST 20  // slice row stride in uints (16 data + 4 pad)

__global__ __launch_bounds__(256) void k_mm(const unsigned* __restrict__ xu,
    const unsigned* __restrict__ Wtb, const float* __restrict__ b1,
    const float* __restrict__ W20, const float* __restrict__ W21,
    float* __restrict__ t, float* __restrict__ s) {
  __shared__ unsigned Ws[2][256 * WS_ST];  // 2 x 20480 B
  const int row0 = blockIdx.x * 64;
  const int tid = threadIdx.x;
  const int w = tid >> 6, lane = tid & 63;
  const int colb = w * 64;
  const int frow = lane & 15, fqo = (lane >> 4) * 4;
  const int c16 = lane & 15, q4 = lane >> 4;

  f32x4 acc[4][4];
#pragma unroll
  for (int a = 0; a < 4; ++a)
#pragma unroll
    for (int b = 0; b < 4; ++b) {
      acc[a][b][0] = 0.f; acc[a][b][1] = 0.f;
      acc[a][b][2] = 0.f; acc[a][b][3] = 0.f;
    }

  const uint4* Wtb4 = (const uint4*)Wtb;
  // prefetch kc=0 slice: thread stages row tid (4 uint4)
  uint4 rw[4];
#pragma unroll
  for (int j = 0; j < 4; ++j) rw[j] = Wtb4[(size_t)tid * 32 + j];

  for (int kc = 0; kc < 8; ++kc) {
    const int b = kc & 1;
    unsigned* dst = Ws[b] + tid * WS_ST;
#pragma unroll
    for (int j = 0; j < 4; ++j) *(uint4*)(dst + j * 4) = rw[j];
    if (kc + 1 < 8) {
#pragma unroll
      for (int j = 0; j < 4; ++j) rw[j] = Wtb4[(size_t)tid * 32 + (kc + 1) * 4 + j];
    }
    __syncthreads();
    short8 af[4], bf[4];
#pragma unroll
    for (int a = 0; a < 4; ++a)
      af[a] = *(const short8*)(xu + (size_t)(row0 + a * 16 + frow) * 128 + kc * 16 + fqo);
#pragma unroll
    for (int n = 0; n < 4; ++n)
      bf[n] = *(const short8*)(Ws[b] + (colb + n * 16 + frow) * WS_ST + fqo);
#pragma unroll
    for (int a = 0; a < 4; ++a)
#pragma unroll
      for (int n = 0; n < 4; ++n)
        acc[a][n] = __builtin_amdgcn_mfma_f32_16x16x32_bf16(af[a], bf[n], acc[a][n], 0, 0, 0);
    __syncthreads();
  }

  // epilogue: relu + project; butterfly over c16; guarded atomics
  float tp[4][4] = {}, sp[4][4] = {};
#pragma unroll
  for (int b2 = 0; b2 < 4; ++b2) {
    int gc = colb + b2 * 16 + c16;
    float w20 = W20[gc], w21 = W21[gc], bb = b1[gc];
#pragma unroll
    for (int a = 0; a < 4; ++a)
#pragma unroll
      for (int r = 0; r < 4; ++r) {
        float val = acc[a][b2][r] + bb;
        val = val > 0.f ? val : 0.f;
        tp[a][r] += val * w20;
        sp[a][r] += val * w21;
      }
  }
#pragma unroll
  for (int a = 0; a < 4; ++a)
#pragma unroll
    for (int r = 0; r < 4; ++r) {
#pragma unroll
      for (int m = 1; m < 16; m <<= 1) {
        tp[a][r] += __shfl_xor(tp[a][r], m, 64);
        sp[a][r] += __shfl_xor(sp[a][r], m, 64);
      }
    }
  if (c16 == 0) {
#pragma unroll
    for (int a = 0; a < 4; ++a)
#pragma unroll
      for (int r = 0; r < 4; ++r) {
        int gr = row0 + a * 16 + q4 * 4 + r;
        if (gr < N_NODES) {
          atomicAdd(&t[gr], tp[a][r]);
          atomicAdd(&s[gr], sp[a][r]);
        }
      }
  }
}

// ---------------- GNN layer 2 scalar gather ----------------

__global__ __launch_bounds__(256) void k_h2(const float* __restrict__ t,
    const float* __restrict__ s, const int* __restrict__ rowstart,
    const int* __restrict__ cols, const float* __restrict__ wvals,
    const float* __restrict__ lamb, const float* __restrict__ b2, float* __restrict__ h2) {
  int i = blockIdx.x * 256 + threadIdx.x;
  if (i >= N_NODES) return;
  float m = 0.f;
  int s0 = rowstart[i], s1 = rowstart[i + 1];
  for (int e = s0; e < s1; ++e) m += wvals[e] * s[cols[e]];
  float val = t[i] + m + b2[0];
  val = val > 0.f ? val : 0.f;
  h2[i] = lamb[0] * val;
}

// ---------------- QP setup: bf16 A^T + b^T A partials ----------------
__global__ __launch_bounds__(256) void k_prep(const float* __restrict__ A,
    const float* __restrict__ b, unsigned* __restrict__ Atu, float* __restrict__ btA_parts) {
  int jp = blockIdx.x * 256 + threadIdx.x;   // 0..1023 col pairs
  int k0 = blockIdx.y * 128;
  const float2* A2 = (const float2*)A;
  float acc0 = 0.f, acc1 = 0.f;
  for (int kk = 0; kk < 128; kk += 8) {
    float ax[8], ay[8];
#pragma unroll
    for (int i = 0; i < 8; ++i) {
      int k = k0 + kk + i;
      float2 a = A2[(size_t)k * 1024 + jp];
      float bk = b[k];
      acc0 += a.x * bk;
      acc1 += a.y * bk;
      ax[i] = a.x; ay[i] = a.y;
    }
    uint4 t0, t1;
    t0.x = f2bf(ax[0]) | (f2bf(ax[1]) << 16);
    t0.y = f2bf(ax[2]) | (f2bf(ax[3]) << 16);
    t0.z = f2bf(ax[4]) | (f2bf(ax[5]) << 16);
    t0.w = f2bf(ax[6]) | (f2bf(ax[7]) << 16);
    t1.x = f2bf(ay[0]) | (f2bf(ay[1]) << 16);
    t1.y = f2bf(ay[2]) | (f2bf(ay[3]) << 16);
    t1.z = f2bf(ay[4]) | (f2bf(ay[5]) << 16);
    t1.w = f2bf(ay[6]) | (f2bf(ay[7]) << 16);
    int uoff = (k0 + kk) >> 1;
    *(uint4*)(Atu + (size_t)(2 * jp) * 2048 + uoff) = t0;
    *(uint4*)(Atu + (size_t)(2 * jp + 1) * 2048 + uoff) = t1;
  }
  ((float2*)(btA_parts + (size_t)blockIdx.y * NQ))[jp] = make_float2(acc0, acc1);
}

// q, r0 = rhs
__global__ __launch_bounds__(256) void k_qrhs(const float* __restrict__ h2,
    const int* __restrict__ feat_ids, const float* __restrict__ x_prior,
    const float* __restrict__ btA_parts, float* __restrict__ q, float* __restrict__ r) {
  int j = blockIdx.x * 256 + threadIdx.x;
  int f = feat_ids[j];
  float hf = h2[f] + 1e-5f;
  q[j] = hf;
  float bta = 0.f;
#pragma unroll
  for (int c = 0; c < 32; ++c) bta += btA_parts[(size_t)c * NQ + j];
  r[j] = x_prior[j] * hf + bta;  // rhs = -p
}

// ---------------- G = A^T A + diag(q), bf16 MFMA, 8 waves/block ----------
// In-block K-split: waves 0-3 (group 0) do even 32-bf16 slices, waves 4-7
// (group 1) odd; wave w and w+4 share the same 64x64 output tile; combine
// via LDS at the end (2 rounds to fit 40 KB). 2 barriers per super-iter.
#define GR_ST 20

__global__ __launch_bounds__(512) void k_gram(const unsigned* __restrict__ Atu,
                                              const float* __restrict__ q,
                                              float* __restrict__ G) {
  __shared__ unsigned shmem[10240];  // 40960 B: [grp][A/B] tiles of 128*GR_ST
  const int i0 = blockIdx.x * 128, j0 = blockIdx.y * 128;
  const int tid = threadIdx.x;       // 0..511
  const int grp = tid >> 8;          // K-half
  const int t8 = tid & 255;
  const int w = tid >> 6;            // 0..7
  const int wt = w & 3;              // tile id
  const int lane = tid & 63;
  const int wr = (wt >> 1) * 64, wc = (wt & 1) * 64;
  const int srow = t8 >> 1, suo = (t8 & 1) * 8;
  const int frow = lane & 15, fqo = (lane >> 4) * 4;

  unsigned* shA = shmem + grp * 5120;
  unsigned* shB = shA + 2560;

  f32x4 acc[4][4];
#pragma unroll
  for (int a = 0; a < 4; ++a)
#pragma unroll
    for (int b = 0; b < 4; ++b) {
      acc[a][b][0] = 0.f; acc[a][b][1] = 0.f;
      acc[a][b][2] = 0.f; acc[a][b][3] = 0.f;
    }

  const unsigned* pa = Atu + (size_t)(i0 + srow) * 2048 + suo;
  const unsigned* pb = Atu + (size_t)(j0 + srow) * 2048 + suo;

  // prefetch si=0 (this group's slice)
  int ku = grp * 16;
  uint4 ra0 = *(const uint4*)(pa + ku);
  uint4 ra1 = *(const uint4*)(pa + ku + 4);
  uint4 rb0 = *(const uint4*)(pb + ku);
  uint4 rb1 = *(const uint4*)(pb + ku + 4);

  for (int si = 0; si < 64; ++si) {
    unsigned* as = shA + srow * GR_ST + suo;
    unsigned* bs = shB + srow * GR_ST + suo;
    *(uint4*)as = ra0; *(uint4*)(as + 4) = ra1;
    *(uint4*)bs = rb0; *(uint4*)(bs + 4) = rb1;
    if (si + 1 < 64) {
      ku = (si + 1) * 32 + grp * 16;
      ra0 = *(const uint4*)(pa + ku);
      ra1 = *(const uint4*)(pa + ku + 4);
      rb0 = *(const uint4*)(pb + ku);
      rb1 = *(const uint4*)(pb + ku + 4);
    }
    __syncthreads();
    short8 af[4], bf[4];
#pragma unroll
    for (int a = 0; a < 4; ++a)
      af[a] = *(const short8*)(shA + (wr + a * 16 + frow) * GR_ST + fqo);
#pragma unroll
    for (int b2 = 0; b2 < 4; ++b2)
      bf[b2] = *(const short8*)(shB + (wc + b2 * 16 + frow) * GR_ST + fqo);
#pragma unroll
    for (int a = 0; a < 4; ++a)
#pragma unroll
      for (int b2 = 0; b2 < 4; ++b2)
        acc[a][b2] = __builtin_amdgcn_mfma_f32_16x16x32_bf16(af[a], bf[b2], acc[a][b2], 0, 0, 0);
    __syncthreads();
  }

  // combine group-1 partials into group-0 accumulators (2 LDS rounds)
  const int q4 = lane >> 4, c16 = lane & 15;
  float* comb = (float*)shmem;  // 10240 floats; 2 tiles x 64x65 = 8320
#pragma unroll
  for (int rnd = 0; rnd < 2; ++rnd) {
    if (grp == 1 && (wt >> 1) == rnd) {
      float* dst = comb + (wt & 1) * 4160;
#pragma unroll
      for (int a = 0; a < 4; ++a)
#pragma unroll
        for (int b2 = 0; b2 < 4; ++b2)
#pragma unroll
          for (int r = 0; r < 4; ++r)
            dst[(a * 16 + q4 * 4 + r) * 65 + b2 * 16 + c16] = acc[a][b2][r];
    }
    __syncthreads();
    if (grp == 0 && (wt >> 1) == rnd) {
      const float* src = comb + (wt & 1) * 4160;
#pragma unroll
      for (int a = 0; a < 4; ++a)
#pragma unroll
        for (int b2 = 0; b2 < 4; ++b2)
#pragma unroll
          for (int r = 0; r < 4; ++r)
            acc[a][b2][r] += src[(a * 16 + q4 * 4 + r) * 65 + b2 * 16 + c16];
    }
    __syncthreads();
  }

  if (grp == 0) {
#pragma unroll
    for (int a = 0; a < 4; ++a)
#pragma unroll
      for (int b2 = 0; b2 < 4; ++b2)
#pragma unroll
        for (int r = 0; r < 4; ++r) {
          int gr = i0 + wr + a * 16 + q4 * 4 + r;
          int gc = j0 + wc + b2 * 16 + c16;
          float val = acc[a][b2][r];
          if (gr == gc) val += q[gr];
          G[(size_t)gr * NQ + gc] = val;
        }
  }
}

// ---------------- CG: ONE kernel/iter.  Qp = G p ------------------------
__global__ __launch_bounds__(256) void k_cgG(int k, const float* __restrict__ G,
    const float* __restrict__ r_old, float* __restrict__ r_new,
    const float* __restrict__ p_old, float* __restrict__ p_new,
    const float* __restrict__ Qp_in, float* __restrict__ Qp_out,
    float* __restrict__ xcg) {
  __shared__ float pshare[NQ];
  __shared__ float lds[4];
  const int tid = threadIdx.x, bid = blockIdx.x;
  const float4* r4 = (const float4*)r_old;
  float4 ra = r4[tid * 2], rb2 = r4[tid * 2 + 1];
  float pv[8];
  if (k == 0) {
    pv[0] = ra.x; pv[1] = ra.y; pv[2] = ra.z; pv[3] = ra.w;
    pv[4] = rb2.x; pv[5] = rb2.y; pv[6] = rb2.z; pv[7] = rb2.w;
    if (bid == 0) {
      ((float4*)p_new)[tid * 2] = ra;
      ((float4*)p_new)[tid * 2 + 1] = rb2;
    }
  } else {
    const float4* p4 = (const float4*)p_old;
    const float4* qp4 = (const float4*)Qp_in;
    float4 pa = p4[tid * 2], pb = p4[tid * 2 + 1];
    float4 qa = qp4[tid * 2], qb = qp4[tid * 2 + 1];
    float rr = ra.x * ra.x + ra.y * ra.y + ra.z * ra.z + ra.w * ra.w +
               rb2.x * rb2.x + rb2.y * rb2.y + rb2.z * rb2.z + rb2.w * rb2.w;
    float pap = pa.x * qa.x + pa.y * qa.y + pa.z * qa.z + pa.w * qa.w +
                pb.x * qb.x + pb.y * qb.y + pb.z * qb.z + pb.w * qb.w;
    rr = bred256(rr, lds);
    pap = bred256(pap, lds);
    float alpha = rr / pap;
    if (bid == 0) {
      float4* x4 = (float4*)xcg;
      float4 xa = x4[tid * 2], xb = x4[tid * 2 + 1];
      xa.x += alpha * pa.x; xa.y += alpha * pa.y;
      xa.z += alpha * pa.z; xa.w += alpha * pa.w;
      xb.x += alpha * pb.x; xb.y += alpha * pb.y;
      xb.z += alpha * pb.z; xb.w += alpha * pb.w;
      x4[tid * 2] = xa; x4[tid * 2 + 1] = xb;
    }
    ra.x -= alpha * qa.x; ra.y -= alpha * qa.y;
    ra.z -= alpha * qa.z; ra.w -= alpha * qa.w;
    rb2.x -= alpha * qb.x; rb2.y -= alpha * qb.y;
    rb2.z -= alpha * qb.z; rb2.w -= alpha * qb.w;
    float rrn = ra.x * ra.x + ra.y * ra.y + ra.z * ra.z + ra.w * ra.w +
                rb2.x * rb2.x + rb2.y * rb2.y + rb2.z * rb2.z + rb2.w * rb2.w;
    rrn = bred256(rrn, lds);
    float beta = rrn / rr;
    pv[0] = ra.x + beta * pa.x; pv[1] = ra.y + beta * pa.y;
    pv[2] = ra.z + beta * pa.z; pv[3] = ra.w + beta * pa.w;
    pv[4] = rb2.x + beta * pb.x; pv[5] = rb2.y + beta * pb.y;
    pv[6] = rb2.z + beta * pb.z; pv[7] = rb2.w + beta * pb.w;
    if (bid == 0) {
      ((float4*)r_new)[tid * 2] = ra;
      ((float4*)r_new)[tid * 2 + 1] = rb2;
      ((float4*)p_new)[tid * 2] = make_float4(pv[0], pv[1], pv[2], pv[3]);
      ((float4*)p_new)[tid * 2 + 1] = make_float4(pv[4], pv[5], pv[6], pv[7]);
    }
  }
  ((float4*)pshare)[tid * 2] = make_float4(pv[0], pv[1], pv[2], pv[3]);
  ((float4*)pshare)[tid * 2 + 1] = make_float4(pv[4], pv[5], pv[6], pv[7]);
  __syncthreads();
  const int w = tid >> 6, lane = tid & 63;
  const int row = bid * 4 + w;
  const float4* Gr = (const float4*)(G + (size_t)row * NQ);
  const float4* ps4 = (const float4*)pshare;
  float acc = 0.f;
#pragma unroll
  for (int c = 0; c < 4; ++c) {
#pragma unroll
    for (int hh = 0; hh < 2; ++hh) {
      int idx = c * 128 + lane * 2 + hh;
      float4 g = Gr[idx];
      float4 pp = ps4[idx];
      acc += g.x * pp.x + g.y * pp.y + g.z * pp.z + g.w * pp.w;
    }
  }
  acc = wred(acc);
  if (lane == 0) Qp_out[row] = acc;
}

// ---------------- final: alpha + out = x + alpha p -----------------------
__global__ __launch_bounds__(256) void k_cgfin(const float* __restrict__ r_last,
    const float* __restrict__ p_last, const float* __restrict__ Qp,
    const float* __restrict__ xcg, float* __restrict__ out) {
  const int tid = threadIdx.x;
  const int lane = tid & 63;
  const float4* r4 = (const float4*)r_last;
  const float4* p4 = (const float4*)p_last;
  const float4* q4 = (const float4*)Qp;
  float rr = 0.f, pap = 0.f;
#pragma unroll
  for (int c = 0; c < 4; ++c) {
#pragma unroll
    for (int hh = 0; hh < 2; ++hh) {
      float4 rv = r4[c * 128 + lane * 2 + hh];
      float4 pv = p4[c * 128 + lane * 2 + hh];
      float4 qv = q4[c * 128 + lane * 2 + hh];
      rr += rv.x * rv.x + rv.y * rv.y + rv.z * rv.z + rv.w * rv.w;
      pap += pv.x * qv.x + pv.y * qv.y + pv.z * qv.z + pv.w * qv.w;
    }
  }
  rr = wred(rr);
  pap = wred(pap);
  float alpha = rr / pap;
  const float4* x4 = (const float4*)xcg;
  float4* o4 = (float4*)out;
#pragma unroll
  for (int hh = 0; hh < 2; ++hh) {
    int i4 = tid * 2 + hh;
    float4 xv = x4[i4];
    float4 pv = p4[i4];
    xv.x += alpha * pv.x; xv.y += alpha * pv.y;
    xv.z += alpha * pv.z; xv.w += alpha * pv.w;
    o4[i4] = xv;
  }
}

// ---------------- launch ----------------

extern "C" void kernel_launch(void* const* d_in, const int* in_sizes, int n_in,
                              void* d_out, int out_size, void* d_ws, size_t ws_size,
                              hipStream_t stream) {
  const float* x      = (const float*)d_in[0];
  const int*   ei     = (const int*)d_in[1];
  const float* A      = (const float*)d_in[2];
  const float* b      = (const float*)d_in[3];
  const int*   fids   = (const int*)d_in[4];
  const float* xprior = (const float*)d_in[5];
  const float* lamb   = (const float*)d_in[6];
  const float* W10    = (const float*)d_in[7];
  const float* W11    = (const float*)d_in[8];
  const float* b1     = (const float*)d_in[9];
  const float* W20    = (const float*)d_in[10];
  const float* W21    = (const float*)d_in[11];
  const float* b2     = (const float*)d_in[12];
  float* out = (float*)d_out;

  char* base = (char*)d_ws;
  size_t o = 0;
  auto alloc = [&](size_t bytes) { size_t r = o; o = (o + bytes + 255) & ~size_t(255); return r; };

  // zero-init region (deg, cursor, xcg, t, s)
  size_t off_deg    = alloc(N_NODES * 4);
  size_t off_cursor = alloc(N_NODES * 4);
  size_t off_xcg    = alloc(NQ * 4);
  size_t off_t      = alloc(N_NODES * 4);
  size_t off_s      = alloc(N_NODES * 4);
  size_t zero_end   = o;
  size_t off_rowst  = alloc((N_NODES + 1) * 4);
  size_t off_dinv   = alloc(N_NODES * 4);
  size_t off_h2     = alloc(N_NODES * 4);
  size_t off_q      = alloc(NQ * 4);
  size_t off_r0     = alloc(NQ * 4);
  size_t off_r1     = alloc(NQ * 4);
  size_t off_p0     = alloc(NQ * 4);
  size_t off_p1     = alloc(NQ * 4);
  size_t off_Qp0    = alloc(NQ * 4);
  size_t off_Qp1    = alloc(NQ * 4);
  size_t off_btAp   = alloc(32 * NQ * 4);
  size_t off_Wtb    = alloc(256 * 128 * 4);
  // union: GNN {cols, wvals, xmsgb} vs QP {Atu}
  size_t sz_cols  = (size_t)N_EDGES * 4 + 256;
  size_t sz_wvals = (size_t)N_EDGES * 4 + 256;
  size_t sz_xmsg  = (size_t)MM_ROWS * 256 * 2;
  size_t union_gnn = sz_cols + sz_wvals + sz_xmsg;
  size_t union_at  = (size_t)M_ROWS * NQ * 2;
  size_t off_union = alloc(union_gnn > union_at ? union_gnn : union_at);
  size_t off_G     = alloc((size_t)NQ * NQ * 4);
  if (o > ws_size) return;

  int*   deg      = (int*)(base + off_deg);
  int*   cursor   = (int*)(base + off_cursor);
  float* xcg      = (float*)(base + off_xcg);
  float* t        = (float*)(base + off_t);
  float* s        = (float*)(base + off_s);
  int*   rowstart = (int*)(base + off_rowst);
  float* dinv     = (float*)(base + off_dinv);
  float* h2       = (float*)(base + off_h2);
  float* q        = (float*)(base + off_q);
  float* rb[2]    = {(float*)(base + off_r0), (float*)(base + off_r1)};
  float* pg[2]    = {(float*)(base + off_p0), (float*)(base + off_p1)};
  float* Qpb[2]   = {(float*)(base + off_Qp0), (float*)(base + off_Qp1)};
  float* btA_parts = (float*)(base + off_btAp);
  unsigned* Wtb   = (unsigned*)(base + off_Wtb);
  int*   cols     = (int*)(base + off_union);
  float* wvals    = (float*)(base + off_union + sz_cols);
  unsigned* xmsgb = (unsigned*)(base + off_union + sz_cols + sz_wvals);
  unsigned* Atu   = (unsigned*)(base + off_union);
  float* G        = (float*)(base + off_G);

  hipMemsetAsync(d_ws, 0, zero_end, stream);

  // CSR build
  k_deg<<<(N_EDGES + 255) / 256, 256, 0, stream>>>(ei, deg);
  k_scan<<<1, 1024, 0, stream>>>(deg, rowstart, dinv);
  k_scatter<<<(N_EDGES + 255) / 256, 256, 0, stream>>>(ei, rowstart, cursor, dinv, cols, wvals);

  // GNN (bf16 MFMA path)
  k_convx<<<MM_ROWS * 16 / 256, 256, 0, stream>>>(x, xmsgb);
  k_msg1<<<N_NODES / 4, 256, 0, stream>>>(x, rowstart, cols, wvals, xmsgb);
  k_prepW<<<128, 256, 0, stream>>>(W10, W11, Wtb);
  k_mm<<<MM_ROWS / 64, 256, 0, stream>>>(xmsgb, Wtb, b1, W20, W21, t, s);
  k_h2<<<(N_NODES + 255) / 256, 256, 0, stream>>>(t, s, rowstart, cols, wvals, lamb, b2, h2);

  // QP setup (after k_h2: Atu overwrites cols/wvals/xmsgb)
  k_prep<<<dim3(4, 32), 256, 0, stream>>>(A, b, Atu, btA_parts);
  k_qrhs<<<NQ / 256, 256, 0, stream>>>(h2, fids, xprior, btA_parts, q, rb[0]);
  k_gram<<<dim3(16, 16), 512, 0, stream>>>(Atu, q, G);

  // CG: 1 kernel/iter
  k_cgG<<<512, 256, 0, stream>>>(0, G, rb[0], rb[0], pg[0], pg[0], Qpb[1], Qpb[0], xcg);
  for (int k = 1; k < NIT; ++k) {
    k_cgG<<<512, 256, 0, stream>>>(k, G, rb[(k - 1) & 1], rb[k & 1],
                                   pg[(k - 1) & 1], pg[k & 1],
                                   Qpb[(k - 1) & 1], Qpb[k & 1], xcg);
  }
  k_cgfin<<<1, 256, 0, stream>>>(rb[(NIT - 1) & 1], pg[(NIT - 1) & 1],
                                 Qpb[(NIT - 1) & 1], xcg, out);
}

// Round 9
// 424.307 us; speedup vs baseline: 7.3629x; 1.0313x over previous
//
#include <hip/hip_runtime.h>

#define N_NODES 20000
#define N_EDGES 320000
#define F_DIM   128
#define H_DIM   256
#define M_ROWS  4096
#define NQ      2048
#define NIT     20
#define MM_ROWS 20032   // 313 * 64, padded row count for bf16 [x|msg]

typedef __attribute__((ext_vector_type(8))) short short8;   // 8 bf16 (4 VGPRs)
typedef __attribute__((ext_vector_type(4))) float f32x4;    // MFMA C/D

// ---------------- helpers ----------------

__device__ __forceinline__ float wred(float v) {
#pragma unroll
  for (int m = 32; m > 0; m >>= 1) v += __shfl_xor(v, m, 64);
  return v;
}

__device__ __forceinline__ float bred256(float v, float* lds) {
  v = wred(v);
  int w = threadIdx.x >> 6;
  if ((threadIdx.x & 63) == 0) lds[w] = v;
  __syncthreads();
  float tot = lds[0] + lds[1] + lds[2] + lds[3];
  __syncthreads();
  return tot;
}

__device__ __forceinline__ unsigned f2bf(float f) {
  unsigned u = __float_as_uint(f);
  unsigned r = u + 0x7fffu + ((u >> 16) & 1u);
  return r >> 16;
}
__device__ __forceinline__ float bflo(unsigned u) { return __uint_as_float(u << 16); }
__device__ __forceinline__ float bfhi(unsigned u) { return __uint_as_float(u & 0xffff0000u); }

// ---------------- CSR build ----------------

__global__ __launch_bounds__(256) void k_deg(const int* __restrict__ ei, int* __restrict__ deg) {
  int e = blockIdx.x * 256 + threadIdx.x;
  if (e < N_EDGES) atomicAdd(&deg[ei[e]], 1);
}

__global__ __launch_bounds__(1024) void k_scan(const int* __restrict__ deg,
    int* __restrict__ rowstart, float* __restrict__ dinv) {
  __shared__ int part[1024];
  int t = threadIdx.x;
  const int chunk = (N_NODES + 1023) / 1024;  // 20
  int lo = t * chunk;
  int hi = lo + chunk; if (hi > N_NODES) hi = N_NODES;
  int s = 0;
  for (int i = lo; i < hi; ++i) {
    int d = deg[i];
    dinv[i] = d > 0 ? rsqrtf((float)d) : 0.f;
    s += d;
  }
  part[t] = s;
  __syncthreads();
  for (int off = 1; off < 1024; off <<= 1) {
    int v = part[t];
    int add = (t >= off) ? part[t - off] : 0;
    __syncthreads();
    part[t] = v + add;
    __syncthreads();
  }
  int base = (t > 0) ? part[t - 1] : 0;
  for (int i = lo; i < hi; ++i) { rowstart[i] = base; base += deg[i]; }
  if (t == 0) rowstart[N_NODES] = part[1023];
}

__global__ __launch_bounds__(256) void k_scatter(const int* __restrict__ ei,
    const int* __restrict__ rowstart, int* __restrict__ cursor,
    const float* __restrict__ dinv, int* __restrict__ cols, float* __restrict__ wvals) {
  int e = blockIdx.x * 256 + threadIdx.x;
  if (e >= N_EDGES) return;
  int r = ei[e];
  int c = ei[N_EDGES + e];
  int pos = rowstart[r] + atomicAdd(&cursor[r], 1);
  cols[pos] = c;
  wvals[pos] = -dinv[r] * dinv[c];
}

// ---------------- bf16 packing of [x | msg] ----------------
// xmsgb: MM_ROWS x 256 bf16 row-major. cols 0..127 = x (bf16), 128..255 = msg.
__global__ __launch_bounds__(256) void k_convx(const float* __restrict__ x,
                                               unsigned* __restrict__ xu) {
  int gid = blockIdx.x * 256 + threadIdx.x;   // MM_ROWS*16 threads
  int row = gid >> 4;
  int q8 = gid & 15;
  uint4* xu4 = (uint4*)xu;
  if (row < N_NODES) {
    const float4* x4 = (const float4*)x;
    float4 a = x4[(size_t)row * 32 + q8 * 2];
    float4 b = x4[(size_t)row * 32 + q8 * 2 + 1];
    uint4 u;
    u.x = f2bf(a.x) | (f2bf(a.y) << 16);
    u.y = f2bf(a.z) | (f2bf(a.w) << 16);
    u.z = f2bf(b.x) | (f2bf(b.y) << 16);
    u.w = f2bf(b.z) | (f2bf(b.w) << 16);
    xu4[(size_t)row * 32 + q8] = u;
  } else {
    uint4 z = make_uint4(0, 0, 0, 0);
    xu4[(size_t)row * 32 + q8] = z;
    xu4[(size_t)row * 32 + 16 + q8] = z;
  }
}

// msg gather from bf16 x half (halved traffic vs fp32 x), bf16 store into
// the msg half. fp32 accumulate.
__global__ __launch_bounds__(256) void k_msg1(const int* __restrict__ rowstart,
    const int* __restrict__ cols, const float* __restrict__ wvals,
    unsigned* __restrict__ xu) {
  int wid = (blockIdx.x * 256 + threadIdx.x) >> 6;
  int lane = threadIdx.x & 63;
  if (wid >= N_NODES) return;
  int s0 = rowstart[wid], s1 = rowstart[wid + 1];
  float2 acc = make_float2(0.f, 0.f);
  for (int e = s0; e < s1; ++e) {
    int c = cols[e];
    float w = wvals[e];
    unsigned u = xu[(size_t)c * 128 + lane];   // cols 2*lane, 2*lane+1 of x
    acc.x += w * bflo(u);
    acc.y += w * bfhi(u);
  }
  xu[(size_t)wid * 128 + 64 + lane] = f2bf(acc.x) | (f2bf(acc.y) << 16);
}

// Wtb[n][k] = bf16( Wcat[k][n] ), n=0..255, k=0..255 (Wcat = [W10;W11]).
__global__ __launch_bounds__(256) void k_prepW(const float* __restrict__ W10,
    const float* __restrict__ W11, unsigned* __restrict__ Wtb) {
  int gid = blockIdx.x * 256 + threadIdx.x;   // 0..32767
  int n = gid >> 7;                            // 0..255
  int u = gid & 127;                           // uint index in row
  int k0 = u * 2;
  float v0 = (k0 < 128) ? W10[(size_t)k0 * H_DIM + n]
                        : W11[(size_t)(k0 - 128) * H_DIM + n];
  float v1 = (k0 + 1 < 128) ? W10[(size_t)(k0 + 1) * H_DIM + n]
                            : W11[(size_t)(k0 - 127) * H_DIM + n];
  Wtb[(size_t)n * 128 + u] = f2bf(v0) | (f2bf(v1) << 16);
}

// ---------------- GNN layer-1 GEMM via MFMA ----------------
#define WS_ST 20  // slice row stride in uints (16 data + 4 pad)

__global__ __launch_bounds__(256) void k_mm(const unsigned* __restrict__ xu,
    const unsigned* __restrict__ Wtb, const float* __restrict__ b1,
    const float* __restrict__ W20, const float* __restrict__ W21,
    float* __restrict__ t, float* __restrict__ s) {
  __shared__ unsigned Ws[2][256 * WS_ST];  // 2 x 20480 B
  const int row0 = blockIdx.x * 64;
  const int tid = threadIdx.x;
  const int w = tid >> 6, lane = tid & 63;
  const int colb = w * 64;
  const int frow = lane & 15, fqo = (lane >> 4) * 4;
  const int c16 = lane & 15, q4 = lane >> 4;

  f32x4 acc[4][4];
#pragma unroll
  for (int a = 0; a < 4; ++a)
#pragma unroll
    for (int b = 0; b < 4; ++b) {
      acc[a][b][0] = 0.f; acc[a][b][1] = 0.f;
      acc[a][b][2] = 0.f; acc[a][b][3] = 0.f;
    }

  const uint4* Wtb4 = (const uint4*)Wtb;
  uint4 rw[4];
#pragma unroll
  for (int j = 0; j < 4; ++j) rw[j] = Wtb4[(size_t)tid * 32 + j];

  for (int kc = 0; kc < 8; ++kc) {
    const int b = kc & 1;
    unsigned* dst = Ws[b] + tid * WS_ST;
#pragma unroll
    for (int j = 0; j < 4; ++j) *(uint4*)(dst + j * 4) = rw[j];
    if (kc + 1 < 8) {
#pragma unroll
      for (int j = 0; j < 4; ++j) rw[j] = Wtb4[(size_t)tid * 32 + (kc + 1) * 4 + j];
    }
    __syncthreads();
    short8 af[4], bf[4];
#pragma unroll
    for (int a = 0; a < 4; ++a)
      af[a] = *(const short8*)(xu + (size_t)(row0 + a * 16 + frow) * 128 + kc * 16 + fqo);
#pragma unroll
    for (int n = 0; n < 4; ++n)
      bf[n] = *(const short8*)(Ws[b] + (colb + n * 16 + frow) * WS_ST + fqo);
#pragma unroll
    for (int a = 0; a < 4; ++a)
#pragma unroll
      for (int n = 0; n < 4; ++n)
        acc[a][n] = __builtin_amdgcn_mfma_f32_16x16x32_bf16(af[a], bf[n], acc[a][n], 0, 0, 0);
    __syncthreads();
  }

  float tp[4][4] = {}, sp[4][4] = {};
#pragma unroll
  for (int b2 = 0; b2 < 4; ++b2) {
    int gc = colb + b2 * 16 + c16;
    float w20 = W20[gc], w21 = W21[gc], bb = b1[gc];
#pragma unroll
    for (int a = 0; a < 4; ++a)
#pragma unroll
      for (int r = 0; r < 4; ++r) {
        float val = acc[a][b2][r] + bb;
        val = val > 0.f ? val : 0.f;
        tp[a][r] += val * w20;
        sp[a][r] += val * w21;
      }
  }
#pragma unroll
  for (int a = 0; a < 4; ++a)
#pragma unroll
    for (int r = 0; r < 4; ++r) {
#pragma unroll
      for (int m = 1; m < 16; m <<= 1) {
        tp[a][r] += __shfl_xor(tp[a][r], m, 64);
        sp[a][r] += __shfl_xor(sp[a][r], m, 64);
      }
    }
  if (c16 == 0) {
#pragma unroll
    for (int a = 0; a < 4; ++a)
#pragma unroll
      for (int r = 0; r < 4; ++r) {
        int gr = row0 + a * 16 + q4 * 4 + r;
        if (gr < N_NODES) {
          atomicAdd(&t[gr], tp[a][r]);
          atomicAdd(&s[gr], sp[a][r]);
        }
      }
  }
}

// ---------------- GNN layer 2 scalar gather ----------------

__global__ __launch_bounds__(256) void k_h2(const float* __restrict__ t,
    const float* __restrict__ s, const int* __restrict__ rowstart,
    const int* __restrict__ cols, const float* __restrict__ wvals,
    const float* __restrict__ lamb, const float* __restrict__ b2, float* __restrict__ h2) {
  int i = blockIdx.x * 256 + threadIdx.x;
  if (i >= N_NODES) return;
  float m = 0.f;
  int s0 = rowstart[i], s1 = rowstart[i + 1];
  for (int e = s0; e < s1; ++e) m += wvals[e] * s[cols[e]];
  float val = t[i] + m + b2[0];
  val = val > 0.f ? val : 0.f;
  h2[i] = lamb[0] * val;
}

// ---------------- QP setup: bf16 A^T + b^T A partials ----------------
__global__ __launch_bounds__(256) void k_prep(const float* __restrict__ A,
    const float* __restrict__ b, unsigned* __restrict__ Atu, float* __restrict__ btA_parts) {
  int jp = blockIdx.x * 256 + threadIdx.x;   // 0..1023 col pairs
  int k0 = blockIdx.y * 128;
  const float2* A2 = (const float2*)A;
  float acc0 = 0.f, acc1 = 0.f;
  for (int kk = 0; kk < 128; kk += 8) {
    float ax[8], ay[8];
#pragma unroll
    for (int i = 0; i < 8; ++i) {
      int k = k0 + kk + i;
      float2 a = A2[(size_t)k * 1024 + jp];
      float bk = b[k];
      acc0 += a.x * bk;
      acc1 += a.y * bk;
      ax[i] = a.x; ay[i] = a.y;
    }
    uint4 t0, t1;
    t0.x = f2bf(ax[0]) | (f2bf(ax[1]) << 16);
    t0.y = f2bf(ax[2]) | (f2bf(ax[3]) << 16);
    t0.z = f2bf(ax[4]) | (f2bf(ax[5]) << 16);
    t0.w = f2bf(ax[6]) | (f2bf(ax[7]) << 16);
    t1.x = f2bf(ay[0]) | (f2bf(ay[1]) << 16);
    t1.y = f2bf(ay[2]) | (f2bf(ay[3]) << 16);
    t1.z = f2bf(ay[4]) | (f2bf(ay[5]) << 16);
    t1.w = f2bf(ay[6]) | (f2bf(ay[7]) << 16);
    int uoff = (k0 + kk) >> 1;
    *(uint4*)(Atu + (size_t)(2 * jp) * 2048 + uoff) = t0;
    *(uint4*)(Atu + (size_t)(2 * jp + 1) * 2048 + uoff) = t1;
  }
  ((float2*)(btA_parts + (size_t)blockIdx.y * NQ))[jp] = make_float2(acc0, acc1);
}

// q, r0 = rhs
__global__ __launch_bounds__(256) void k_qrhs(const float* __restrict__ h2,
    const int* __restrict__ feat_ids, const float* __restrict__ x_prior,
    const float* __restrict__ btA_parts, float* __restrict__ q, float* __restrict__ r) {
  int j = blockIdx.x * 256 + threadIdx.x;
  int f = feat_ids[j];
  float hf = h2[f] + 1e-5f;
  q[j] = hf;
  float bta = 0.f;
#pragma unroll
  for (int c = 0; c < 32; ++c) bta += btA_parts[(size_t)c * NQ + j];
  r[j] = x_prior[j] * hf + bta;  // rhs = -p
}

// ---------------- G = A^T A + diag(q), bf16 MFMA, 8 waves/block ----------
#define GR_ST 20

__global__ __launch_bounds__(512) void k_gram(const unsigned* __restrict__ Atu,
                                              const float* __restrict__ q,
                                              float* __restrict__ G) {
  __shared__ unsigned shmem[10240];  // 40960 B
  const int i0 = blockIdx.x * 128, j0 = blockIdx.y * 128;
  const int tid = threadIdx.x;       // 0..511
  const int grp = tid >> 8;          // K-half
  const int t8 = tid & 255;
  const int w = tid >> 6;            // 0..7
  const int wt = w & 3;              // tile id
  const int lane = tid & 63;
  const int wr = (wt >> 1) * 64, wc = (wt & 1) * 64;
  const int srow = t8 >> 1, suo = (t8 & 1) * 8;
  const int frow = lane & 15, fqo = (lane >> 4) * 4;

  unsigned* shA = shmem + grp * 5120;
  unsigned* shB = shA + 2560;

  f32x4 acc[4][4];
#pragma unroll
  for (int a = 0; a < 4; ++a)
#pragma unroll
    for (int b = 0; b < 4; ++b) {
      acc[a][b][0] = 0.f; acc[a][b][1] = 0.f;
      acc[a][b][2] = 0.f; acc[a][b][3] = 0.f;
    }

  const unsigned* pa = Atu + (size_t)(i0 + srow) * 2048 + suo;
  const unsigned* pb = Atu + (size_t)(j0 + srow) * 2048 + suo;

  int ku = grp * 16;
  uint4 ra0 = *(const uint4*)(pa + ku);
  uint4 ra1 = *(const uint4*)(pa + ku + 4);
  uint4 rb0 = *(const uint4*)(pb + ku);
  uint4 rb1 = *(const uint4*)(pb + ku + 4);

  for (int si = 0; si < 64; ++si) {
    unsigned* as = shA + srow * GR_ST + suo;
    unsigned* bs = shB + srow * GR_ST + suo;
    *(uint4*)as = ra0; *(uint4*)(as + 4) = ra1;
    *(uint4*)bs = rb0; *(uint4*)(bs + 4) = rb1;
    if (si + 1 < 64) {
      ku = (si + 1) * 32 + grp * 16;
      ra0 = *(const uint4*)(pa + ku);
      ra1 = *(const uint4*)(pa + ku + 4);
      rb0 = *(const uint4*)(pb + ku);
      rb1 = *(const uint4*)(pb + ku + 4);
    }
    __syncthreads();
    short8 af[4], bf[4];
#pragma unroll
    for (int a = 0; a < 4; ++a)
      af[a] = *(const short8*)(shA + (wr + a * 16 + frow) * GR_ST + fqo);
#pragma unroll
    for (int b2 = 0; b2 < 4; ++b2)
      bf[b2] = *(const short8*)(shB + (wc + b2 * 16 + frow) * GR_ST + fqo);
#pragma unroll
    for (int a = 0; a < 4; ++a)
#pragma unroll
      for (int b2 = 0; b2 < 4; ++b2)
        acc[a][b2] = __builtin_amdgcn_mfma_f32_16x16x32_bf16(af[a], bf[b2], acc[a][b2], 0, 0, 0);
    __syncthreads();
  }

  const int q4 = lane >> 4, c16 = lane & 15;
  float* comb = (float*)shmem;
#pragma unroll
  for (int rnd = 0; rnd < 2; ++rnd) {
    if (grp == 1 && (wt >> 1) == rnd) {
      float* dst = comb + (wt & 1) * 4160;
#pragma unroll
      for (int a = 0; a < 4; ++a)
#pragma unroll
        for (int b2 = 0; b2 < 4; ++b2)
#pragma unroll
          for (int r = 0; r < 4; ++r)
            dst[(a * 16 + q4 * 4 + r) * 65 + b2 * 16 + c16] = acc[a][b2][r];
    }
    __syncthreads();
    if (grp == 0 && (wt >> 1) == rnd) {
      const float* src = comb + (wt & 1) * 4160;
#pragma unroll
      for (int a = 0; a < 4; ++a)
#pragma unroll
        for (int b2 = 0; b2 < 4; ++b2)
#pragma unroll
          for (int r = 0; r < 4; ++r)
            acc[a][b2][r] += src[(a * 16 + q4 * 4 + r) * 65 + b2 * 16 + c16];
    }
    __syncthreads();
  }

  if (grp == 0) {
#pragma unroll
    for (int a = 0; a < 4; ++a)
#pragma unroll
      for (int b2 = 0; b2 < 4; ++b2)
#pragma unroll
        for (int r = 0; r < 4; ++r) {
          int gr = i0 + wr + a * 16 + q4 * 4 + r;
          int gc = j0 + wc + b2 * 16 + c16;
          float val = acc[a][b2][r];
          if (gr == gc) val += q[gr];
          G[(size_t)gr * NQ + gc] = val;
        }
  }
}

// ---------------- fp32 G -> bf16 Gb + fp32 diag correction ----------------
// block = row; thread covers 8 cols. qcorr[row] = G_ii - bf16(G_ii).
__global__ __launch_bounds__(256) void k_gconv(const float* __restrict__ G,
    unsigned* __restrict__ Gb, float* __restrict__ qcorr) {
  int row = blockIdx.x;
  int tid = threadIdx.x;
  const float4* g4 = (const float4*)(G + (size_t)row * NQ);
  float4 a = g4[tid * 2], b = g4[tid * 2 + 1];
  uint4 u;
  u.x = f2bf(a.x) | (f2bf(a.y) << 16);
  u.y = f2bf(a.z) | (f2bf(a.w) << 16);
  u.z = f2bf(b.x) | (f2bf(b.y) << 16);
  u.w = f2bf(b.z) | (f2bf(b.w) << 16);
  ((uint4*)(Gb + (size_t)row * 1024))[tid] = u;
  if ((row >> 3) == tid) {
    float vals[8] = {a.x, a.y, a.z, a.w, b.x, b.y, b.z, b.w};
    float v = vals[row & 7];
    qcorr[row] = v - __uint_as_float(f2bf(v) << 16);
  }
}

// ---------------- CG: ONE kernel/iter.  Qp = Gb p + qcorr*p --------------
__global__ __launch_bounds__(256) void k_cgG(int k, const unsigned* __restrict__ Gb,
    const float* __restrict__ qcorr,
    const float* __restrict__ r_old, float* __restrict__ r_new,
    const float* __restrict__ p_old, float* __restrict__ p_new,
    const float* __restrict__ Qp_in, float* __restrict__ Qp_out,
    float* __restrict__ xcg) {
  __shared__ float pshare[NQ];
  __shared__ float lds[4];
  const int tid = threadIdx.x, bid = blockIdx.x;
  const float4* r4 = (const float4*)r_old;
  float4 ra = r4[tid * 2], rb2 = r4[tid * 2 + 1];
  float pv[8];
  if (k == 0) {
    pv[0] = ra.x; pv[1] = ra.y; pv[2] = ra.z; pv[3] = ra.w;
    pv[4] = rb2.x; pv[5] = rb2.y; pv[6] = rb2.z; pv[7] = rb2.w;
    if (bid == 0) {
      ((float4*)p_new)[tid * 2] = ra;
      ((float4*)p_new)[tid * 2 + 1] = rb2;
    }
  } else {
    const float4* p4 = (const float4*)p_old;
    const float4* qp4 = (const float4*)Qp_in;
    float4 pa = p4[tid * 2], pb = p4[tid * 2 + 1];
    float4 qa = qp4[tid * 2], qb = qp4[tid * 2 + 1];
    float rr = ra.x * ra.x + ra.y * ra.y + ra.z * ra.z + ra.w * ra.w +
               rb2.x * rb2.x + rb2.y * rb2.y + rb2.z * rb2.z + rb2.w * rb2.w;
    float pap = pa.x * qa.x + pa.y * qa.y + pa.z * qa.z + pa.w * qa.w +
                pb.x * qb.x + pb.y * qb.y + pb.z * qb.z + pb.w * qb.w;
    rr = bred256(rr, lds);
    pap = bred256(pap, lds);
    float alpha = rr / pap;
    if (bid == 0) {
      float4* x4 = (float4*)xcg;
      float4 xa = x4[tid * 2], xb = x4[tid * 2 + 1];
      xa.x += alpha * pa.x; xa.y += alpha * pa.y;
      xa.z += alpha * pa.z; xa.w += alpha * pa.w;
      xb.x += alpha * pb.x; xb.y += alpha * pb.y;
      xb.z += alpha * pb.z; xb.w += alpha * pb.w;
      x4[tid * 2] = xa; x4[tid * 2 + 1] = xb;
    }
    ra.x -= alpha * qa.x; ra.y -= alpha * qa.y;
    ra.z -= alpha * qa.z; ra.w -= alpha * qa.w;
    rb2.x -= alpha * qb.x; rb2.y -= alpha * qb.y;
    rb2.z -= alpha * qb.z; rb2.w -= alpha * qb.w;
    float rrn = ra.x * ra.x + ra.y * ra.y + ra.z * ra.z + ra.w * ra.w +
                rb2.x * rb2.x + rb2.y * rb2.y + rb2.z * rb2.z + rb2.w * rb2.w;
    rrn = bred256(rrn, lds);
    float beta = rrn / rr;
    pv[0] = ra.x + beta * pa.x; pv[1] = ra.y + beta * pa.y;
    pv[2] = ra.z + beta * pa.z; pv[3] = ra.w + beta * pa.w;
    pv[4] = rb2.x + beta * pb.x; pv[5] = rb2.y + beta * pb.y;
    pv[6] = rb2.z + beta * pb.z; pv[7] = rb2.w + beta * pb.w;
    if (bid == 0) {
      ((float4*)r_new)[tid * 2] = ra;
      ((float4*)r_new)[tid * 2 + 1] = rb2;
      ((float4*)p_new)[tid * 2] = make_float4(pv[0], pv[1], pv[2], pv[3]);
      ((float4*)p_new)[tid * 2 + 1] = make_float4(pv[4], pv[5], pv[6], pv[7]);
    }
  }
  ((float4*)pshare)[tid * 2] = make_float4(pv[0], pv[1], pv[2], pv[3]);
  ((float4*)pshare)[tid * 2 + 1] = make_float4(pv[4], pv[5], pv[6], pv[7]);
  __syncthreads();
  // matvec: one bf16 G-row per wave (+ fp32 diag correction)
  const int w = tid >> 6, lane = tid & 63;
  const int row = bid * 4 + w;
  const uint4* Gr = (const uint4*)(Gb + (size_t)row * 1024);
  const float4* ps4 = (const float4*)pshare;
  float acc = 0.f;
#pragma unroll
  for (int c = 0; c < 4; ++c) {
    uint4 gv = Gr[c * 64 + lane];
    float4 pa = ps4[c * 128 + lane * 2];
    float4 pb = ps4[c * 128 + lane * 2 + 1];
    acc += bflo(gv.x) * pa.x + bfhi(gv.x) * pa.y;
    acc += bflo(gv.y) * pa.z + bfhi(gv.y) * pa.w;
    acc += bflo(gv.z) * pb.x + bfhi(gv.z) * pb.y;
    acc += bflo(gv.w) * pb.z + bfhi(gv.w) * pb.w;
  }
  acc = wred(acc);
  if (lane == 0) Qp_out[row] = acc + qcorr[row] * pshare[row];
}

// ---------------- final: alpha + out = x + alpha p -----------------------
__global__ __launch_bounds__(256) void k_cgfin(const float* __restrict__ r_last,
    const float* __restrict__ p_last, const float* __restrict__ Qp,
    const float* __restrict__ xcg, float* __restrict__ out) {
  const int tid = threadIdx.x;
  const int lane = tid & 63;
  const float4* r4 = (const float4*)r_last;
  const float4* p4 = (const float4*)p_last;
  const float4* q4 = (const float4*)Qp;
  float rr = 0.f, pap = 0.f;
#pragma unroll
  for (int c = 0; c < 4; ++c) {
#pragma unroll
    for (int hh = 0; hh < 2; ++hh) {
      float4 rv = r4[c * 128 + lane * 2 + hh];
      float4 pv = p4[c * 128 + lane * 2 + hh];
      float4 qv = q4[c * 128 + lane * 2 + hh];
      rr += rv.x * rv.x + rv.y * rv.y + rv.z * rv.z + rv.w * rv.w;
      pap += pv.x * qv.x + pv.y * qv.y + pv.z * qv.z + pv.w * qv.w;
    }
  }
  rr = wred(rr);
  pap = wred(pap);
  float alpha = rr / pap;
  const float4* x4 = (const float4*)xcg;
  float4* o4 = (float4*)out;
#pragma unroll
  for (int hh = 0; hh < 2; ++hh) {
    int i4 = tid * 2 + hh;
    float4 xv = x4[i4];
    float4 pv = p4[i4];
    xv.x += alpha * pv.x; xv.y += alpha * pv.y;
    xv.z += alpha * pv.z; xv.w += alpha * pv.w;
    o4[i4] = xv;
  }
}

// ---------------- launch ----------------

extern "C" void kernel_launch(void* const* d_in, const int* in_sizes, int n_in,
                              void* d_out, int out_size, void* d_ws, size_t ws_size,
                              hipStream_t stream) {
  const float* x      = (const float*)d_in[0];
  const int*   ei     = (const int*)d_in[1];
  const float* A      = (const float*)d_in[2];
  const float* b      = (const float*)d_in[3];
  const int*   fids   = (const int*)d_in[4];
  const float* xprior = (const float*)d_in[5];
  const float* lamb   = (const float*)d_in[6];
  const float* W10    = (const float*)d_in[7];
  const float* W11    = (const float*)d_in[8];
  const float* b1     = (const float*)d_in[9];
  const float* W20    = (const float*)d_in[10];
  const float* W21    = (const float*)d_in[11];
  const float* b2     = (const float*)d_in[12];
  float* out = (float*)d_out;

  char* base = (char*)d_ws;
  size_t o = 0;
  auto alloc = [&](size_t bytes) { size_t r = o; o = (o + bytes + 255) & ~size_t(255); return r; };

  // zero-init region (deg, cursor, xcg, t, s)
  size_t off_deg    = alloc(N_NODES * 4);
  size_t off_cursor = alloc(N_NODES * 4);
  size_t off_xcg    = alloc(NQ * 4);
  size_t off_t      = alloc(N_NODES * 4);
  size_t off_s      = alloc(N_NODES * 4);
  size_t zero_end   = o;
  size_t off_rowst  = alloc((N_NODES + 1) * 4);
  size_t off_dinv   = alloc(N_NODES * 4);
  size_t off_h2     = alloc(N_NODES * 4);
  size_t off_q      = alloc(NQ * 4);
  size_t off_r0     = alloc(NQ * 4);
  size_t off_r1     = alloc(NQ * 4);
  size_t off_p0     = alloc(NQ * 4);
  size_t off_p1     = alloc(NQ * 4);
  size_t off_Qp0    = alloc(NQ * 4);
  size_t off_Qp1    = alloc(NQ * 4);
  size_t off_qcorr  = alloc(NQ * 4);
  size_t off_btAp   = alloc(32 * NQ * 4);
  size_t off_Wtb    = alloc(256 * 128 * 4);
  // union: GNN {cols, wvals, xmsgb} vs QP {Atu}
  size_t sz_cols  = (size_t)N_EDGES * 4 + 256;
  size_t sz_wvals = (size_t)N_EDGES * 4 + 256;
  size_t sz_xmsg  = (size_t)MM_ROWS * 256 * 2;
  size_t union_gnn = sz_cols + sz_wvals + sz_xmsg;
  size_t union_at  = (size_t)M_ROWS * NQ * 2;
  size_t off_union = alloc(union_gnn > union_at ? union_gnn : union_at);
  size_t off_G     = alloc((size_t)NQ * NQ * 4);
  size_t off_Gb    = alloc((size_t)NQ * NQ * 2);
  if (o > ws_size) return;

  int*   deg      = (int*)(base + off_deg);
  int*   cursor   = (int*)(base + off_cursor);
  float* xcg      = (float*)(base + off_xcg);
  float* t        = (float*)(base + off_t);
  float* s        = (float*)(base + off_s);
  int*   rowstart = (int*)(base + off_rowst);
  float* dinv     = (float*)(base + off_dinv);
  float* h2       = (float*)(base + off_h2);
  float* q        = (float*)(base + off_q);
  float* rb[2]    = {(float*)(base + off_r0), (float*)(base + off_r1)};
  float* pg[2]    = {(float*)(base + off_p0), (float*)(base + off_p1)};
  float* Qpb[2]   = {(float*)(base + off_Qp0), (float*)(base + off_Qp1)};
  float* qcorr    = (float*)(base + off_qcorr);
  float* btA_parts = (float*)(base + off_btAp);
  unsigned* Wtb   = (unsigned*)(base + off_Wtb);
  int*   cols     = (int*)(base + off_union);
  float* wvals    = (float*)(base + off_union + sz_cols);
  unsigned* xmsgb = (unsigned*)(base + off_union + sz_cols + sz_wvals);
  unsigned* Atu   = (unsigned*)(base + off_union);
  float* G        = (float*)(base + off_G);
  unsigned* Gb    = (unsigned*)(base + off_Gb);

  hipMemsetAsync(d_ws, 0, zero_end, stream);

  // CSR build
  k_deg<<<(N_EDGES + 255) / 256, 256, 0, stream>>>(ei, deg);
  k_scan<<<1, 1024, 0, stream>>>(deg, rowstart, dinv);
  k_scatter<<<(N_EDGES + 255) / 256, 256, 0, stream>>>(ei, rowstart, cursor, dinv, cols, wvals);

  // GNN (bf16 MFMA path)
  k_convx<<<MM_ROWS * 16 / 256, 256, 0, stream>>>(x, xmsgb);
  k_msg1<<<N_NODES / 4, 256, 0, stream>>>(rowstart, cols, wvals, xmsgb);
  k_prepW<<<128, 256, 0, stream>>>(W10, W11, Wtb);
  k_mm<<<MM_ROWS / 64, 256, 0, stream>>>(xmsgb, Wtb, b1, W20, W21, t, s);
  k_h2<<<(N_NODES + 255) / 256, 256, 0, stream>>>(t, s, rowstart, cols, wvals, lamb, b2, h2);

  // QP setup (after k_h2: Atu overwrites cols/wvals/xmsgb)
  k_prep<<<dim3(4, 32), 256, 0, stream>>>(A, b, Atu, btA_parts);
  k_qrhs<<<NQ / 256, 256, 0, stream>>>(h2, fids, xprior, btA_parts, q, rb[0]);
  k_gram<<<dim3(16, 16), 512, 0, stream>>>(Atu, q, G);
  k_gconv<<<NQ, 256, 0, stream>>>(G, Gb, qcorr);

  // CG: 1 kernel/iter
  k_cgG<<<512, 256, 0, stream>>>(0, Gb, qcorr, rb[0], rb[0], pg[0], pg[0],
                                 Qpb[1], Qpb[0], xcg);
  for (int k = 1; k < NIT; ++k) {
    k_cgG<<<512, 256, 0, stream>>>(k, Gb, qcorr, rb[(k - 1) & 1], rb[k & 1],
                                   pg[(k - 1) & 1], pg[k & 1],
                                   Qpb[(k - 1) & 1], Qpb[k & 1], xcg);
  }
  k_cgfin<<<1, 256, 0, stream>>>(rb[(NIT - 1) & 1], pg[(NIT - 1) & 1],
                                 Qpb[(NIT - 1) & 1], xcg, out);
}

// Round 10
// 412.881 us; speedup vs baseline: 7.5666x; 1.0277x over previous
//
#include <hip/hip_runtime.h>

#define N_NODES 20000
#define N_EDGES 320000
#define F_DIM   128
#define H_DIM   256
#define M_ROWS  4096
#define NQ      2048
#define NIT     18
#define MM_ROWS 20032   // 313 * 64, padded row count for bf16 [x|msg]

typedef __attribute__((ext_vector_type(8))) short short8;   // 8 bf16 (4 VGPRs)
typedef __attribute__((ext_vector_type(4))) float f32x4;    // MFMA C/D

// ---------------- helpers ----------------

__device__ __forceinline__ float wred(float v) {
#pragma unroll
  for (int m = 32; m > 0; m >>= 1) v += __shfl_xor(v, m, 64);
  return v;
}

__device__ __forceinline__ float bred256(float v, float* lds) {
  v = wred(v);
  int w = threadIdx.x >> 6;
  if ((threadIdx.x & 63) == 0) lds[w] = v;
  __syncthreads();
  float tot = lds[0] + lds[1] + lds[2] + lds[3];
  __syncthreads();
  return tot;
}

__device__ __forceinline__ unsigned f2bf(float f) {
  unsigned u = __float_as_uint(f);
  unsigned r = u + 0x7fffu + ((u >> 16) & 1u);
  return r >> 16;
}
__device__ __forceinline__ float bflo(unsigned u) { return __uint_as_float(u << 16); }
__device__ __forceinline__ float bfhi(unsigned u) { return __uint_as_float(u & 0xffff0000u); }

// ---------------- CSR build ----------------

__global__ __launch_bounds__(256) void k_deg(const int* __restrict__ ei, int* __restrict__ deg) {
  int e = blockIdx.x * 256 + threadIdx.x;
  if (e < N_EDGES) atomicAdd(&deg[ei[e]], 1);
}

__global__ __launch_bounds__(1024) void k_scan(const int* __restrict__ deg,
    int* __restrict__ rowstart, float* __restrict__ dinv) {
  __shared__ int part[1024];
  int t = threadIdx.x;
  const int chunk = (N_NODES + 1023) / 1024;  // 20
  int lo = t * chunk;
  int hi = lo + chunk; if (hi > N_NODES) hi = N_NODES;
  int s = 0;
  for (int i = lo; i < hi; ++i) {
    int d = deg[i];
    dinv[i] = d > 0 ? rsqrtf((float)d) : 0.f;
    s += d;
  }
  part[t] = s;
  __syncthreads();
  for (int off = 1; off < 1024; off <<= 1) {
    int v = part[t];
    int add = (t >= off) ? part[t - off] : 0;
    __syncthreads();
    part[t] = v + add;
    __syncthreads();
  }
  int base = (t > 0) ? part[t - 1] : 0;
  for (int i = lo; i < hi; ++i) { rowstart[i] = base; base += deg[i]; }
  if (t == 0) rowstart[N_NODES] = part[1023];
}

__global__ __launch_bounds__(256) void k_scatter(const int* __restrict__ ei,
    const int* __restrict__ rowstart, int* __restrict__ cursor,
    const float* __restrict__ dinv, int* __restrict__ cols, float* __restrict__ wvals) {
  int e = blockIdx.x * 256 + threadIdx.x;
  if (e >= N_EDGES) return;
  int r = ei[e];
  int c = ei[N_EDGES + e];
  int pos = rowstart[r] + atomicAdd(&cursor[r], 1);
  cols[pos] = c;
  wvals[pos] = -dinv[r] * dinv[c];
}

// ---------------- bf16 packing: x half of xmsgb + Wtb (fused) ------------
// xmsgb: MM_ROWS x 256 bf16 row-major. cols 0..127 = x (bf16), 128..255 = msg.
// Wtb[n][k] = bf16( Wcat[k][n] ), Wcat = [W10;W11], 256x256.
#define CONVX_BLKS (MM_ROWS * 16 / 256)   // 1252

__global__ __launch_bounds__(256) void k_pack(const float* __restrict__ x,
    const float* __restrict__ W10, const float* __restrict__ W11,
    unsigned* __restrict__ xu, unsigned* __restrict__ Wtb) {
  int bx = blockIdx.x;
  if (bx < CONVX_BLKS) {
    int gid = bx * 256 + threadIdx.x;
    int row = gid >> 4;
    int q8 = gid & 15;
    uint4* xu4 = (uint4*)xu;
    if (row < N_NODES) {
      const float4* x4 = (const float4*)x;
      float4 a = x4[(size_t)row * 32 + q8 * 2];
      float4 b = x4[(size_t)row * 32 + q8 * 2 + 1];
      uint4 u;
      u.x = f2bf(a.x) | (f2bf(a.y) << 16);
      u.y = f2bf(a.z) | (f2bf(a.w) << 16);
      u.z = f2bf(b.x) | (f2bf(b.y) << 16);
      u.w = f2bf(b.z) | (f2bf(b.w) << 16);
      xu4[(size_t)row * 32 + q8] = u;
    } else {
      uint4 z = make_uint4(0, 0, 0, 0);
      xu4[(size_t)row * 32 + q8] = z;
      xu4[(size_t)row * 32 + 16 + q8] = z;
    }
  } else {
    int gid = (bx - CONVX_BLKS) * 256 + threadIdx.x;  // 0..32767
    int n = gid >> 7;
    int u = gid & 127;
    int k0 = u * 2;
    float v0 = (k0 < 128) ? W10[(size_t)k0 * H_DIM + n]
                          : W11[(size_t)(k0 - 128) * H_DIM + n];
    float v1 = (k0 + 1 < 128) ? W10[(size_t)(k0 + 1) * H_DIM + n]
                              : W11[(size_t)(k0 - 127) * H_DIM + n];
    Wtb[(size_t)n * 128 + u] = f2bf(v0) | (f2bf(v1) << 16);
  }
}

// msg gather from bf16 x half, bf16 store into the msg half. fp32 accumulate.
__global__ __launch_bounds__(256) void k_msg1(const int* __restrict__ rowstart,
    const int* __restrict__ cols, const float* __restrict__ wvals,
    unsigned* __restrict__ xu) {
  int wid = (blockIdx.x * 256 + threadIdx.x) >> 6;
  int lane = threadIdx.x & 63;
  if (wid >= N_NODES) return;
  int s0 = rowstart[wid], s1 = rowstart[wid + 1];
  float2 acc = make_float2(0.f, 0.f);
  for (int e = s0; e < s1; ++e) {
    int c = cols[e];
    float w = wvals[e];
    unsigned u = xu[(size_t)c * 128 + lane];
    acc.x += w * bflo(u);
    acc.y += w * bfhi(u);
  }
  xu[(size_t)wid * 128 + 64 + lane] = f2bf(acc.x) | (f2bf(acc.y) << 16);
}

// ---------------- GNN layer-1 GEMM via MFMA ----------------
#define WS_ST 20  // slice row stride in uints (16 data + 4 pad)

__global__ __launch_bounds__(256) void k_mm(const unsigned* __restrict__ xu,
    const unsigned* __restrict__ Wtb, const float* __restrict__ b1,
    const float* __restrict__ W20, const float* __restrict__ W21,
    float* __restrict__ t, float* __restrict__ s) {
  __shared__ unsigned Ws[2][256 * WS_ST];  // 2 x 20480 B
  const int row0 = blockIdx.x * 64;
  const int tid = threadIdx.x;
  const int w = tid >> 6, lane = tid & 63;
  const int colb = w * 64;
  const int frow = lane & 15, fqo = (lane >> 4) * 4;
  const int c16 = lane & 15, q4 = lane >> 4;

  f32x4 acc[4][4];
#pragma unroll
  for (int a = 0; a < 4; ++a)
#pragma unroll
    for (int b = 0; b < 4; ++b) {
      acc[a][b][0] = 0.f; acc[a][b][1] = 0.f;
      acc[a][b][2] = 0.f; acc[a][b][3] = 0.f;
    }

  const uint4* Wtb4 = (const uint4*)Wtb;
  uint4 rw[4];
#pragma unroll
  for (int j = 0; j < 4; ++j) rw[j] = Wtb4[(size_t)tid * 32 + j];

  for (int kc = 0; kc < 8; ++kc) {
    const int b = kc & 1;
    unsigned* dst = Ws[b] + tid * WS_ST;
#pragma unroll
    for (int j = 0; j < 4; ++j) *(uint4*)(dst + j * 4) = rw[j];
    if (kc + 1 < 8) {
#pragma unroll
      for (int j = 0; j < 4; ++j) rw[j] = Wtb4[(size_t)tid * 32 + (kc + 1) * 4 + j];
    }
    __syncthreads();
    short8 af[4], bf[4];
#pragma unroll
    for (int a = 0; a < 4; ++a)
      af[a] = *(const short8*)(xu + (size_t)(row0 + a * 16 + frow) * 128 + kc * 16 + fqo);
#pragma unroll
    for (int n = 0; n < 4; ++n)
      bf[n] = *(const short8*)(Ws[b] + (colb + n * 16 + frow) * WS_ST + fqo);
#pragma unroll
    for (int a = 0; a < 4; ++a)
#pragma unroll
      for (int n = 0; n < 4; ++n)
        acc[a][n] = __builtin_amdgcn_mfma_f32_16x16x32_bf16(af[a], bf[n], acc[a][n], 0, 0, 0);
    __syncthreads();
  }

  float tp[4][4] = {}, sp[4][4] = {};
#pragma unroll
  for (int b2 = 0; b2 < 4; ++b2) {
    int gc = colb + b2 * 16 + c16;
    float w20 = W20[gc], w21 = W21[gc], bb = b1[gc];
#pragma unroll
    for (int a = 0; a < 4; ++a)
#pragma unroll
      for (int r = 0; r < 4; ++r) {
        float val = acc[a][b2][r] + bb;
        val = val > 0.f ? val : 0.f;
        tp[a][r] += val * w20;
        sp[a][r] += val * w21;
      }
  }
#pragma unroll
  for (int a = 0; a < 4; ++a)
#pragma unroll
    for (int r = 0; r < 4; ++r) {
#pragma unroll
      for (int m = 1; m < 16; m <<= 1) {
        tp[a][r] += __shfl_xor(tp[a][r], m, 64);
        sp[a][r] += __shfl_xor(sp[a][r], m, 64);
      }
    }
  if (c16 == 0) {
#pragma unroll
    for (int a = 0; a < 4; ++a)
#pragma unroll
      for (int r = 0; r < 4; ++r) {
        int gr = row0 + a * 16 + q4 * 4 + r;
        if (gr < N_NODES) {
          atomicAdd(&t[gr], tp[a][r]);
          atomicAdd(&s[gr], sp[a][r]);
        }
      }
  }
}

// ---------------- GNN layer 2 scalar gather ----------------

__global__ __launch_bounds__(256) void k_h2(const float* __restrict__ t,
    const float* __restrict__ s, const int* __restrict__ rowstart,
    const int* __restrict__ cols, const float* __restrict__ wvals,
    const float* __restrict__ lamb, const float* __restrict__ b2, float* __restrict__ h2) {
  int i = blockIdx.x * 256 + threadIdx.x;
  if (i >= N_NODES) return;
  float m = 0.f;
  int s0 = rowstart[i], s1 = rowstart[i + 1];
  for (int e = s0; e < s1; ++e) m += wvals[e] * s[cols[e]];
  float val = t[i] + m + b2[0];
  val = val > 0.f ? val : 0.f;
  h2[i] = lamb[0] * val;
}

// ---------------- QP setup: bf16 A^T + b^T A partials ----------------
__global__ __launch_bounds__(256) void k_prep(const float* __restrict__ A,
    const float* __restrict__ b, unsigned* __restrict__ Atu, float* __restrict__ btA_parts) {
  int jp = blockIdx.x * 256 + threadIdx.x;   // 0..1023 col pairs
  int k0 = blockIdx.y * 128;
  const float2* A2 = (const float2*)A;
  float acc0 = 0.f, acc1 = 0.f;
  for (int kk = 0; kk < 128; kk += 8) {
    float ax[8], ay[8];
#pragma unroll
    for (int i = 0; i < 8; ++i) {
      int k = k0 + kk + i;
      float2 a = A2[(size_t)k * 1024 + jp];
      float bk = b[k];
      acc0 += a.x * bk;
      acc1 += a.y * bk;
      ax[i] = a.x; ay[i] = a.y;
    }
    uint4 t0, t1;
    t0.x = f2bf(ax[0]) | (f2bf(ax[1]) << 16);
    t0.y = f2bf(ax[2]) | (f2bf(ax[3]) << 16);
    t0.z = f2bf(ax[4]) | (f2bf(ax[5]) << 16);
    t0.w = f2bf(ax[6]) | (f2bf(ax[7]) << 16);
    t1.x = f2bf(ay[0]) | (f2bf(ay[1]) << 16);
    t1.y = f2bf(ay[2]) | (f2bf(ay[3]) << 16);
    t1.z = f2bf(ay[4]) | (f2bf(ay[5]) << 16);
    t1.w = f2bf(ay[6]) | (f2bf(ay[7]) << 16);
    int uoff = (k0 + kk) >> 1;
    *(uint4*)(Atu + (size_t)(2 * jp) * 2048 + uoff) = t0;
    *(uint4*)(Atu + (size_t)(2 * jp + 1) * 2048 + uoff) = t1;
  }
  ((float2*)(btA_parts + (size_t)blockIdx.y * NQ))[jp] = make_float2(acc0, acc1);
}

// q, r0 = rhs
__global__ __launch_bounds__(256) void k_qrhs(const float* __restrict__ h2,
    const int* __restrict__ feat_ids, const float* __restrict__ x_prior,
    const float* __restrict__ btA_parts, float* __restrict__ q, float* __restrict__ r) {
  int j = blockIdx.x * 256 + threadIdx.x;
  int f = feat_ids[j];
  float hf = h2[f] + 1e-5f;
  q[j] = hf;
  float bta = 0.f;
#pragma unroll
  for (int c = 0; c < 32; ++c) bta += btA_parts[(size_t)c * NQ + j];
  r[j] = x_prior[j] * hf + bta;  // rhs = -p
}

// ---------------- G partials = A^T A (K-split), bf16 MFMA ----------------
// grid (16,16,2): z = K-half (2048 of 4096). 8 waves/block, in-block K-split
// between wave groups as before. 2 blocks/CU co-resident (VGPR 68, 40 KB LDS)
// give 16 waves/CU of latency hiding. Diag(q) moved to k_gconv.
#define GR_ST 20

__global__ __launch_bounds__(512) void k_gram(const unsigned* __restrict__ Atu,
                                              float* __restrict__ Gp) {
  __shared__ unsigned shmem[10240];  // 40960 B
  const int i0 = blockIdx.x * 128, j0 = blockIdx.y * 128;
  const int kz = blockIdx.z;         // K-half: uints [kz*1024, kz*1024+1024)
  const int tid = threadIdx.x;       // 0..511
  const int grp = tid >> 8;          // in-block K-quarter
  const int t8 = tid & 255;
  const int w = tid >> 6;            // 0..7
  const int wt = w & 3;              // tile id
  const int lane = tid & 63;
  const int wr = (wt >> 1) * 64, wc = (wt & 1) * 64;
  const int srow = t8 >> 1, suo = (t8 & 1) * 8;
  const int frow = lane & 15, fqo = (lane >> 4) * 4;

  unsigned* shA = shmem + grp * 5120;
  unsigned* shB = shA + 2560;

  f32x4 acc[4][4];
#pragma unroll
  for (int a = 0; a < 4; ++a)
#pragma unroll
    for (int b = 0; b < 4; ++b) {
      acc[a][b][0] = 0.f; acc[a][b][1] = 0.f;
      acc[a][b][2] = 0.f; acc[a][b][3] = 0.f;
    }

  const unsigned* pa = Atu + (size_t)(i0 + srow) * 2048 + kz * 1024 + suo;
  const unsigned* pb = Atu + (size_t)(j0 + srow) * 2048 + kz * 1024 + suo;

  int ku = grp * 16;
  uint4 ra0 = *(const uint4*)(pa + ku);
  uint4 ra1 = *(const uint4*)(pa + ku + 4);
  uint4 rb0 = *(const uint4*)(pb + ku);
  uint4 rb1 = *(const uint4*)(pb + ku + 4);

  for (int si = 0; si < 32; ++si) {
    unsigned* as = shA + srow * GR_ST + suo;
    unsigned* bs = shB + srow * GR_ST + suo;
    *(uint4*)as = ra0; *(uint4*)(as + 4) = ra1;
    *(uint4*)bs = rb0; *(uint4*)(bs + 4) = rb1;
    if (si + 1 < 32) {
      ku = (si + 1) * 32 + grp * 16;
      ra0 = *(const uint4*)(pa + ku);
      ra1 = *(const uint4*)(pa + ku + 4);
      rb0 = *(const uint4*)(pb + ku);
      rb1 = *(const uint4*)(pb + ku + 4);
    }
    __syncthreads();
    short8 af[4], bf[4];
#pragma unroll
    for (int a = 0; a < 4; ++a)
      af[a] = *(const short8*)(shA + (wr + a * 16 + frow) * GR_ST + fqo);
#pragma unroll
    for (int b2 = 0; b2 < 4; ++b2)
      bf[b2] = *(const short8*)(shB + (wc + b2 * 16 + frow) * GR_ST + fqo);
#pragma unroll
    for (int a = 0; a < 4; ++a)
#pragma unroll
      for (int b2 = 0; b2 < 4; ++b2)
        acc[a][b2] = __builtin_amdgcn_mfma_f32_16x16x32_bf16(af[a], bf[b2], acc[a][b2], 0, 0, 0);
    __syncthreads();
  }

  const int q4 = lane >> 4, c16 = lane & 15;
  float* comb = (float*)shmem;
#pragma unroll
  for (int rnd = 0; rnd < 2; ++rnd) {
    if (grp == 1 && (wt >> 1) == rnd) {
      float* dst = comb + (wt & 1) * 4160;
#pragma unroll
      for (int a = 0; a < 4; ++a)
#pragma unroll
        for (int b2 = 0; b2 < 4; ++b2)
#pragma unroll
          for (int r = 0; r < 4; ++r)
            dst[(a * 16 + q4 * 4 + r) * 65 + b2 * 16 + c16] = acc[a][b2][r];
    }
    __syncthreads();
    if (grp == 0 && (wt >> 1) == rnd) {
      const float* src = comb + (wt & 1) * 4160;
#pragma unroll
      for (int a = 0; a < 4; ++a)
#pragma unroll
        for (int b2 = 0; b2 < 4; ++b2)
#pragma unroll
          for (int r = 0; r < 4; ++r)
            acc[a][b2][r] += src[(a * 16 + q4 * 4 + r) * 65 + b2 * 16 + c16];
    }
    __syncthreads();
  }

  if (grp == 0) {
    float* Gz = Gp + (size_t)kz * NQ * NQ;
#pragma unroll
    for (int a = 0; a < 4; ++a)
#pragma unroll
      for (int b2 = 0; b2 < 4; ++b2)
#pragma unroll
        for (int r = 0; r < 4; ++r) {
          int gr = i0 + wr + a * 16 + q4 * 4 + r;
          int gc = j0 + wc + b2 * 16 + c16;
          Gz[(size_t)gr * NQ + gc] = acc[a][b2][r];
        }
  }
}

// ---------------- combine K-halves + diag(q) -> bf16 Gb + fp32 qcorr -----
// block = row; thread covers 8 cols.
__global__ __launch_bounds__(256) void k_gconv(const float* __restrict__ G0,
    const float* __restrict__ G1, const float* __restrict__ q,
    unsigned* __restrict__ Gb, float* __restrict__ qcorr) {
  int row = blockIdx.x;
  int tid = threadIdx.x;
  const float4* g04 = (const float4*)(G0 + (size_t)row * NQ);
  const float4* g14 = (const float4*)(G1 + (size_t)row * NQ);
  float4 a0 = g04[tid * 2], b0 = g04[tid * 2 + 1];
  float4 a1 = g14[tid * 2], b1 = g14[tid * 2 + 1];
  float v[8] = {a0.x + a1.x, a0.y + a1.y, a0.z + a1.z, a0.w + a1.w,
                b0.x + b1.x, b0.y + b1.y, b0.z + b1.z, b0.w + b1.w};
  bool diag = ((row >> 3) == tid);
  if (diag) v[row & 7] += q[row];
  uint4 u;
  u.x = f2bf(v[0]) | (f2bf(v[1]) << 16);
  u.y = f2bf(v[2]) | (f2bf(v[3]) << 16);
  u.z = f2bf(v[4]) | (f2bf(v[5]) << 16);
  u.w = f2bf(v[6]) | (f2bf(v[7]) << 16);
  ((uint4*)(Gb + (size_t)row * 1024))[tid] = u;
  if (diag) {
    float vd = v[row & 7];
    qcorr[row] = vd - __uint_as_float(f2bf(vd) << 16);
  }
}

// ---------------- CG: ONE kernel/iter.  Qp = Gb p + qcorr*p --------------
__global__ __launch_bounds__(256) void k_cgG(int k, const unsigned* __restrict__ Gb,
    const float* __restrict__ qcorr,
    const float* __restrict__ r_old, float* __restrict__ r_new,
    const float* __restrict__ p_old, float* __restrict__ p_new,
    const float* __restrict__ Qp_in, float* __restrict__ Qp_out,
    float* __restrict__ xcg) {
  __shared__ float pshare[NQ];
  __shared__ float lds[4];
  const int tid = threadIdx.x, bid = blockIdx.x;
  const float4* r4 = (const float4*)r_old;
  float4 ra = r4[tid * 2], rb2 = r4[tid * 2 + 1];
  float pv[8];
  if (k == 0) {
    pv[0] = ra.x; pv[1] = ra.y; pv[2] = ra.z; pv[3] = ra.w;
    pv[4] = rb2.x; pv[5] = rb2.y; pv[6] = rb2.z; pv[7] = rb2.w;
    if (bid == 0) {
      ((float4*)p_new)[tid * 2] = ra;
      ((float4*)p_new)[tid * 2 + 1] = rb2;
    }
  } else {
    const float4* p4 = (const float4*)p_old;
    const float4* qp4 = (const float4*)Qp_in;
    float4 pa = p4[tid * 2], pb = p4[tid * 2 + 1];
    float4 qa = qp4[tid * 2], qb = qp4[tid * 2 + 1];
    float rr = ra.x * ra.x + ra.y * ra.y + ra.z * ra.z + ra.w * ra.w +
               rb2.x * rb2.x + rb2.y * rb2.y + rb2.z * rb2.z + rb2.w * rb2.w;
    float pap = pa.x * qa.x + pa.y * qa.y + pa.z * qa.z + pa.w * qa.w +
                pb.x * qb.x + pb.y * qb.y + pb.z * qb.z + pb.w * qb.w;
    rr = bred256(rr, lds);
    pap = bred256(pap, lds);
    float alpha = rr / pap;
    if (bid == 0) {
      float4* x4 = (float4*)xcg;
      float4 xa = x4[tid * 2], xb = x4[tid * 2 + 1];
      xa.x += alpha * pa.x; xa.y += alpha * pa.y;
      xa.z += alpha * pa.z; xa.w += alpha * pa.w;
      xb.x += alpha * pb.x; xb.y += alpha * pb.y;
      xb.z += alpha * pb.z; xb.w += alpha * pb.w;
      x4[tid * 2] = xa; x4[tid * 2 + 1] = xb;
    }
    ra.x -= alpha * qa.x; ra.y -= alpha * qa.y;
    ra.z -= alpha * qa.z; ra.w -= alpha * qa.w;
    rb2.x -= alpha * qb.x; rb2.y -= alpha * qb.y;
    rb2.z -= alpha * qb.z; rb2.w -= alpha * qb.w;
    float rrn = ra.x * ra.x + ra.y * ra.y + ra.z * ra.z + ra.w * ra.w +
                rb2.x * rb2.x + rb2.y * rb2.y + rb2.z * rb2.z + rb2.w * rb2.w;
    rrn = bred256(rrn, lds);
    float beta = rrn / rr;
    pv[0] = ra.x + beta * pa.x; pv[1] = ra.y + beta * pa.y;
    pv[2] = ra.z + beta * pa.z; pv[3] = ra.w + beta * pa.w;
    pv[4] = rb2.x + beta * pb.x; pv[5] = rb2.y + beta * pb.y;
    pv[6] = rb2.z + beta * pb.z; pv[7] = rb2.w + beta * pb.w;
    if (bid == 0) {
      ((float4*)r_new)[tid * 2] = ra;
      ((float4*)r_new)[tid * 2 + 1] = rb2;
      ((float4*)p_new)[tid * 2] = make_float4(pv[0], pv[1], pv[2], pv[3]);
      ((float4*)p_new)[tid * 2 + 1] = make_float4(pv[4], pv[5], pv[6], pv[7]);
    }
  }
  ((float4*)pshare)[tid * 2] = make_float4(pv[0], pv[1], pv[2], pv[3]);
  ((float4*)pshare)[tid * 2 + 1] = make_float4(pv[4], pv[5], pv[6], pv[7]);
  __syncthreads();
  // matvec: one bf16 G-row per wave (+ fp32 diag correction)
  const int w = tid >> 6, lane = tid & 63;
  const int row = bid * 4 + w;
  const uint4* Gr = (const uint4*)(Gb + (size_t)row * 1024);
  const float4* ps4 = (const float4*)pshare;
  float acc = 0.f;
#pragma unroll
  for (int c = 0; c < 4; ++c) {
    uint4 gv = Gr[c * 64 + lane];
    float4 pa = ps4[c * 128 + lane * 2];
    float4 pb = ps4[c * 128 + lane * 2 + 1];
    acc += bflo(gv.x) * pa.x + bfhi(gv.x) * pa.y;
    acc += bflo(gv.y) * pa.z + bfhi(gv.y) * pa.w;
    acc += bflo(gv.z) * pb.x + bfhi(gv.z) * pb.y;
    acc += bflo(gv.w) * pb.z + bfhi(gv.w) * pb.w;
  }
  acc = wred(acc);
  if (lane == 0) Qp_out[row] = acc + qcorr[row] * pshare[row];
}

// ---------------- final: alpha + out = x + alpha p -----------------------
__global__ __launch_bounds__(256) void k_cgfin(const float* __restrict__ r_last,
    const float* __restrict__ p_last, const float* __restrict__ Qp,
    const float* __restrict__ xcg, float* __restrict__ out) {
  const int tid = threadIdx.x;
  const int lane = tid & 63;
  const float4* r4 = (const float4*)r_last;
  const float4* p4 = (const float4*)p_last;
  const float4* q4 = (const float4*)Qp;
  float rr = 0.f, pap = 0.f;
#pragma unroll
  for (int c = 0; c < 4; ++c) {
#pragma unroll
    for (int hh = 0; hh < 2; ++hh) {
      float4 rv = r4[c * 128 + lane * 2 + hh];
      float4 pv = p4[c * 128 + lane * 2 + hh];
      float4 qv = q4[c * 128 + lane * 2 + hh];
      rr += rv.x * rv.x + rv.y * rv.y + rv.z * rv.z + rv.w * rv.w;
      pap += pv.x * qv.x + pv.y * qv.y + pv.z * qv.z + pv.w * qv.w;
    }
  }
  rr = wred(rr);
  pap = wred(pap);
  float alpha = rr / pap;
  const float4* x4 = (const float4*)xcg;
  float4* o4 = (float4*)out;
#pragma unroll
  for (int hh = 0; hh < 2; ++hh) {
    int i4 = tid * 2 + hh;
    float4 xv = x4[i4];
    float4 pv = p4[i4];
    xv.x += alpha * pv.x; xv.y += alpha * pv.y;
    xv.z += alpha * pv.z; xv.w += alpha * pv.w;
    o4[i4] = xv;
  }
}

// ---------------- launch ----------------

extern "C" void kernel_launch(void* const* d_in, const int* in_sizes, int n_in,
                              void* d_out, int out_size, void* d_ws, size_t ws_size,
                              hipStream_t stream) {
  const float* x      = (const float*)d_in[0];
  const int*   ei     = (const int*)d_in[1];
  const float* A      = (const float*)d_in[2];
  const float* b      = (const float*)d_in[3];
  const int*   fids   = (const int*)d_in[4];
  const float* xprior = (const float*)d_in[5];
  const float* lamb   = (const float*)d_in[6];
  const float* W10    = (const float*)d_in[7];
  const float* W11    = (const float*)d_in[8];
  const float* b1     = (const float*)d_in[9];
  const float* W20    = (const float*)d_in[10];
  const float* W21    = (const float*)d_in[11];
  const float* b2     = (const float*)d_in[12];
  float* out = (float*)d_out;

  char* base = (char*)d_ws;
  size_t o = 0;
  auto alloc = [&](size_t bytes) { size_t r = o; o = (o + bytes + 255) & ~size_t(255); return r; };

  // zero-init region (deg, cursor, xcg, t, s)
  size_t off_deg    = alloc(N_NODES * 4);
  size_t off_cursor = alloc(N_NODES * 4);
  size_t off_xcg    = alloc(NQ * 4);
  size_t off_t      = alloc(N_NODES * 4);
  size_t off_s      = alloc(N_NODES * 4);
  size_t zero_end   = o;
  size_t off_rowst  = alloc((N_NODES + 1) * 4);
  size_t off_dinv   = alloc(N_NODES * 4);
  size_t off_h2     = alloc(N_NODES * 4);
  size_t off_q      = alloc(NQ * 4);
  size_t off_r0     = alloc(NQ * 4);
  size_t off_r1     = alloc(NQ * 4);
  size_t off_p0     = alloc(NQ * 4);
  size_t off_p1     = alloc(NQ * 4);
  size_t off_Qp0    = alloc(NQ * 4);
  size_t off_Qp1    = alloc(NQ * 4);
  size_t off_qcorr  = alloc(NQ * 4);
  size_t off_btAp   = alloc(32 * NQ * 4);
  size_t off_Wtb    = alloc(256 * 128 * 4);
  // union region: GNN {cols, wvals, xmsgb} -> Atu (QP) -> Gb (CG)
  size_t sz_cols  = (size_t)N_EDGES * 4 + 256;
  size_t sz_wvals = (size_t)N_EDGES * 4 + 256;
  size_t sz_xmsg  = (size_t)MM_ROWS * 256 * 2;
  size_t union_gnn = sz_cols + sz_wvals + sz_xmsg;
  size_t union_at  = (size_t)M_ROWS * NQ * 2;
  size_t off_union = alloc(union_gnn > union_at ? union_gnn : union_at);
  size_t off_G0    = alloc((size_t)NQ * NQ * 4);
  size_t off_G1    = alloc((size_t)NQ * NQ * 4);
  if (o > ws_size) return;

  int*   deg      = (int*)(base + off_deg);
  int*   cursor   = (int*)(base + off_cursor);
  float* xcg      = (float*)(base + off_xcg);
  float* t        = (float*)(base + off_t);
  float* s        = (float*)(base + off_s);
  int*   rowstart = (int*)(base + off_rowst);
  float* dinv     = (float*)(base + off_dinv);
  float* h2       = (float*)(base + off_h2);
  float* q        = (float*)(base + off_q);
  float* rb[2]    = {(float*)(base + off_r0), (float*)(base + off_r1)};
  float* pg[2]    = {(float*)(base + off_p0), (float*)(base + off_p1)};
  float* Qpb[2]   = {(float*)(base + off_Qp0), (float*)(base + off_Qp1)};
  float* qcorr    = (float*)(base + off_qcorr);
  float* btA_parts = (float*)(base + off_btAp);
  unsigned* Wtb   = (unsigned*)(base + off_Wtb);
  int*   cols     = (int*)(base + off_union);
  float* wvals    = (float*)(base + off_union + sz_cols);
  unsigned* xmsgb = (unsigned*)(base + off_union + sz_cols + sz_wvals);
  unsigned* Atu   = (unsigned*)(base + off_union);
  unsigned* Gb    = (unsigned*)(base + off_union);  // reuses Atu region after k_gram
  float* G0       = (float*)(base + off_G0);
  float* G1       = (float*)(base + off_G1);

  hipMemsetAsync(d_ws, 0, zero_end, stream);

  // CSR build
  k_deg<<<(N_EDGES + 255) / 256, 256, 0, stream>>>(ei, deg);
  k_scan<<<1, 1024, 0, stream>>>(deg, rowstart, dinv);
  k_scatter<<<(N_EDGES + 255) / 256, 256, 0, stream>>>(ei, rowstart, cursor, dinv, cols, wvals);

  // GNN (bf16 MFMA path)
  k_pack<<<CONVX_BLKS + 128, 256, 0, stream>>>(x, W10, W11, xmsgb, Wtb);
  k_msg1<<<N_NODES / 4, 256, 0, stream>>>(rowstart, cols, wvals, xmsgb);
  k_mm<<<MM_ROWS / 64, 256, 0, stream>>>(xmsgb, Wtb, b1, W20, W21, t, s);
  k_h2<<<(N_NODES + 255) / 256, 256, 0, stream>>>(t, s, rowstart, cols, wvals, lamb, b2, h2);

  // QP setup (after k_h2: Atu overwrites cols/wvals/xmsgb)
  k_prep<<<dim3(4, 32), 256, 0, stream>>>(A, b, Atu, btA_parts);
  k_qrhs<<<NQ / 256, 256, 0, stream>>>(h2, fids, xprior, btA_parts, q, rb[0]);
  k_gram<<<dim3(16, 16, 2), 512, 0, stream>>>(Atu, G0);  // G0/G1 contiguous: z=1 writes G0+NQ*NQ
  k_gconv<<<NQ, 256, 0, stream>>>(G0, G1, q, Gb, qcorr); // Gb overwrites Atu (dead)

  // CG: 1 kernel/iter
  k_cgG<<<512, 256, 0, stream>>>(0, Gb, qcorr, rb[0], rb[0], pg[0], pg[0],
                                 Qpb[1], Qpb[0], xcg);
  for (int k = 1; k < NIT; ++k) {
    k_cgG<<<512, 256, 0, stream>>>(k, Gb, qcorr, rb[(k - 1) & 1], rb[k & 1],
                                   pg[(k - 1) & 1], pg[k & 1],
                                   Qpb[(k - 1) & 1], Qpb[k & 1], xcg);
  }
  k_cgfin<<<1, 256, 0, stream>>>(rb[(NIT - 1) & 1], pg[(NIT - 1) & 1],
                                 Qpb[(NIT - 1) & 1], xcg, out);
}